// Round 6
// baseline (300.285 us; speedup 1.0000x reference)
//
#include <hip/hip_runtime.h>
#include <math.h>

// ---- problem dims (B=2, T=2048, C=1024, H=16, HS=64) ----
#define BB 2
#define TT 2048
#define CC 1024
#define HH 16
#define HS 64
#define MT 4096   // B*T
#define FF 4096   // 4*C

typedef unsigned short u16;
typedef __bf16 bfrag __attribute__((ext_vector_type(8)));
typedef float f4 __attribute__((ext_vector_type(4)));

#define AS1(p) ((const __attribute__((address_space(1))) void*)(p))
#define AS3(p) ((__attribute__((address_space(3))) void*)(p))

__device__ __forceinline__ u16 f2bf(float f) {
  union { float f; unsigned u; } a; a.f = f;
  return (u16)((a.u + 0x7fffu + ((a.u >> 16) & 1u)) >> 16);
}

// XOR-swizzle for 128-byte-row LDS tiles: spreads 8 consecutive rows across
// 8 distinct 16B slots -> wave64 ds_read_b128 at 2-way aliasing (free).
__device__ __forceinline__ int swz128(int byteoff) {
  return byteoff ^ (((byteoff >> 7) & 7) << 4);
}

// XOR-swizzle for 64-byte-row LDS tiles (old GEMM core)
__device__ __forceinline__ int swzAB(int byteoff) {
  return byteoff ^ (((byteoff >> 7) & 3) << 4);
}

// ------------------------------------------------------------------
// Tiled transpose f32 -> bf16.
// ------------------------------------------------------------------
__global__ void tr_f32_bf16(const float* __restrict__ src, u16* __restrict__ dst,
                            int R, int Cc, long long sb, long long db, int dld) {
  __shared__ float t[32][33];
  const int bz = blockIdx.z;
  const int r0 = blockIdx.y * 32, c0 = blockIdx.x * 32;
  const int tx = threadIdx.x, ty = threadIdx.y;
  const float* s = src + bz * sb;
  u16* d = dst + bz * db;
#pragma unroll
  for (int i = 0; i < 4; i++)
    t[ty + i * 8][tx] = s[(size_t)(r0 + ty + i * 8) * Cc + c0 + tx];
  __syncthreads();
#pragma unroll
  for (int i = 0; i < 4; i++)
    d[(size_t)(c0 + ty + i * 8) * dld + r0 + tx] = f2bf(t[tx][ty + i * 8]);
}

// bf16 -> bf16 transpose (for V)
__global__ void tr_bf16(const u16* __restrict__ src, u16* __restrict__ dst,
                        int R, int Cc, long long sb, long long db, int dld) {
  __shared__ u16 t[32][33];
  const int bz = blockIdx.z;
  const int r0 = blockIdx.y * 32, c0 = blockIdx.x * 32;
  const int tx = threadIdx.x, ty = threadIdx.y;
  const u16* s = src + bz * sb;
  u16* d = dst + bz * db;
#pragma unroll
  for (int i = 0; i < 4; i++)
    t[ty + i * 8][tx] = s[(size_t)(r0 + ty + i * 8) * Cc + c0 + tx];
  __syncthreads();
#pragma unroll
  for (int i = 0; i < 4; i++)
    d[(size_t)(c0 + ty + i * 8) * dld + r0 + tx] = t[tx][ty + i * 8];
}

// ------------------------------------------------------------------
// LayerNorm: one block (256 thr) per row of [4096][1024] f32 -> bf16
// ------------------------------------------------------------------
__global__ __launch_bounds__(256) void ln_kernel(
    const float* __restrict__ x, const float* __restrict__ w,
    const float* __restrict__ b, u16* __restrict__ y) {
  const int row = blockIdx.x, tid = threadIdx.x;
  const float4 v = reinterpret_cast<const float4*>(x + (size_t)row * CC)[tid];
  float s = v.x + v.y + v.z + v.w;
  float s2 = v.x * v.x + v.y * v.y + v.z * v.z + v.w * v.w;
#pragma unroll
  for (int off = 32; off >= 1; off >>= 1) {
    s += __shfl_xor(s, off);
    s2 += __shfl_xor(s2, off);
  }
  __shared__ float ps[4], ps2[4];
  const int wave = tid >> 6, lane = tid & 63;
  if (lane == 0) { ps[wave] = s; ps2[wave] = s2; }
  __syncthreads();
  s = ps[0] + ps[1] + ps[2] + ps[3];
  s2 = ps2[0] + ps2[1] + ps2[2] + ps2[3];
  const float mu = s * (1.f / CC);
  const float rstd = rsqrtf(s2 * (1.f / CC) - mu * mu + 1e-5f);
  const float4 wv = reinterpret_cast<const float4*>(w)[tid];
  const float4 bv = reinterpret_cast<const float4*>(b)[tid];
  ushort4 o;
  o.x = f2bf((v.x - mu) * rstd * wv.x + bv.x);
  o.y = f2bf((v.y - mu) * rstd * wv.y + bv.y);
  o.z = f2bf((v.z - mu) * rstd * wv.z + bv.z);
  o.w = f2bf((v.w - mu) * rstd * wv.w + bv.w);
  reinterpret_cast<ushort4*>(y + (size_t)row * CC)[tid] = o;
}

// ------------------------------------------------------------------
// 256x256 phased GEMM core (m201-template mechanics, plain HIP).
// BK=64, 512 thr = 8 waves (2M x 4N), wave tile 128x64 = acc[8][4].
// Double-buffered 128KB LDS, swz128 both-sides; all 8 next-tile
// global_load_lds issued before a counted vmcnt(8); 4 phases/K-tile:
// {ds_read frags; s_barrier; lgkmcnt(0); setprio(1); 16 MFMA; setprio(0);
//  s_barrier}.
// ------------------------------------------------------------------
__device__ __forceinline__ void gemm256_core(
    const u16* __restrict__ A, const u16* __restrict__ Bt, int K,
    f4 (&acc)[8][4]) {
  __shared__ u16 As[2][256 * 64];
  __shared__ u16 Bs[2][256 * 64];
  const int tid = threadIdx.x;            // 0..511
  const int wave = tid >> 6, lane = tid & 63;
  const int wm = wave >> 2, wn = wave & 3;
  const int lg = lane >> 4, ll = lane & 15;

  // staging: LINEAR dest (8KB rounds), inverse-swizzled global source chunk
  const int trow = tid >> 3;               // 0..63
  const int tch  = (tid & 7) ^ (trow & 7); // source chunk 0..7 (16B units)
  const u16* ga = A + (size_t)(blockIdx.y * 256 + trow) * K + tch * 8;
  const u16* gb = Bt + (size_t)(blockIdx.x * 256 + trow) * K + tch * 8;
  const size_t gs = (size_t)64 * K;        // 64-row stride
  const int nt = K >> 6;

  auto STAGE = [&](int bi, int kt) {
    u16* la = &As[bi][tid * 8];
    u16* lb = &Bs[bi][tid * 8];
    const u16* gA = ga + kt * 64;
    const u16* gB = gb + kt * 64;
#pragma unroll
    for (int j = 0; j < 4; j++)
      __builtin_amdgcn_global_load_lds(AS1(gA + j * gs), AS3(la + j * 4096), 16, 0, 0);
#pragma unroll
    for (int j = 0; j < 4; j++)
      __builtin_amdgcn_global_load_lds(AS1(gB + j * gs), AS3(lb + j * 4096), 16, 0, 0);
  };

  STAGE(0, 0);
  int cur = 0;
  for (int t = 0; t < nt; t++) {
    if (t + 1 < nt) {
      STAGE(cur ^ 1, t + 1);   // issue next tile NOW; stays in flight all phases
      asm volatile("s_waitcnt vmcnt(8)" ::: "memory");  // this tile's 8 done
    } else {
      asm volatile("s_waitcnt vmcnt(0)" ::: "memory");
    }
    __builtin_amdgcn_s_barrier();          // staging visible to all waves
    __builtin_amdgcn_sched_barrier(0);

    const char* as_ = (const char*)As[cur];
    const char* bs_ = (const char*)Bs[cur];

#pragma unroll
    for (int kh = 0; kh < 2; kh++) {
      // ---- phase A: M-half 0 ----
      bfrag bf[4], af[4];
#pragma unroll
      for (int j = 0; j < 4; j++)
        bf[j] = *(const bfrag*)(bs_ + swz128((wn * 64 + j * 16 + ll) * 128 + kh * 64 + lg * 16));
#pragma unroll
      for (int i = 0; i < 4; i++)
        af[i] = *(const bfrag*)(as_ + swz128((wm * 128 + i * 16 + ll) * 128 + kh * 64 + lg * 16));
      __builtin_amdgcn_s_barrier();
      asm volatile("s_waitcnt lgkmcnt(0)" ::: "memory");
      __builtin_amdgcn_sched_barrier(0);
      __builtin_amdgcn_s_setprio(1);
#pragma unroll
      for (int i = 0; i < 4; i++)
#pragma unroll
        for (int j = 0; j < 4; j++)
          acc[i][j] = __builtin_amdgcn_mfma_f32_16x16x32_bf16(af[i], bf[j], acc[i][j], 0, 0, 0);
      __builtin_amdgcn_s_setprio(0);
      __builtin_amdgcn_sched_barrier(0);
      __builtin_amdgcn_s_barrier();
      // ---- phase B: M-half 1 ----
#pragma unroll
      for (int i = 0; i < 4; i++)
        af[i] = *(const bfrag*)(as_ + swz128((wm * 128 + 64 + i * 16 + ll) * 128 + kh * 64 + lg * 16));
      __builtin_amdgcn_s_barrier();
      asm volatile("s_waitcnt lgkmcnt(0)" ::: "memory");
      __builtin_amdgcn_sched_barrier(0);
      __builtin_amdgcn_s_setprio(1);
#pragma unroll
      for (int i = 0; i < 4; i++)
#pragma unroll
        for (int j = 0; j < 4; j++)
          acc[4 + i][j] = __builtin_amdgcn_mfma_f32_16x16x32_bf16(af[i], bf[j], acc[4 + i][j], 0, 0, 0);
      __builtin_amdgcn_s_setprio(0);
      __builtin_amdgcn_sched_barrier(0);
      __builtin_amdgcn_s_barrier();
    }
    cur ^= 1;
  }
}

// QKV on 256^2 core: A=xn [4096][1024], Bt=wqkv [3072][1024].
// grid (12, 16), 512 thr.
__global__ __launch_bounds__(512, 2) void gemm_qkv(
    const u16* __restrict__ A, const u16* __restrict__ Bt,
    const float* __restrict__ bq, const float* __restrict__ bk,
    const float* __restrict__ bv,
    u16* __restrict__ q, u16* __restrict__ k, u16* __restrict__ v) {
  f4 acc[8][4] = {};
  gemm256_core(A, Bt, CC, acc);
  const int tid = threadIdx.x;
  const int wave = tid >> 6, lane = tid & 63;
  const int wm = wave >> 2, wn = wave & 3;
  const int lg = lane >> 4, ll = lane & 15;
#pragma unroll
  for (int j = 0; j < 4; j++) {
    const int n = blockIdx.x * 256 + wn * 64 + j * 16 + ll;
    const int sec = n >> 10, nn = n & 1023, h = nn >> 6, d = nn & 63;
    const float bias = (sec == 0 ? bq : (sec == 1 ? bk : bv))[nn];
    const float scale = (sec == 0) ? 0.03125f : 1.0f;  // C^-0.5 folded into Q
    u16* dst = sec == 0 ? q : (sec == 1 ? k : v);
#pragma unroll
    for (int i = 0; i < 8; i++)
#pragma unroll
      for (int r = 0; r < 4; r++) {
        const int m = blockIdx.y * 256 + wm * 128 + i * 16 + lg * 4 + r;
        const int b = m >> 11, t = m & 2047;
        dst[(((size_t)b * HH + h) * TT + t) * HS + d] = f2bf((acc[i][j][r] + bias) * scale);
      }
  }
}

// FFN1 on 256^2 core: h = gelu_exact(A @ W1 + b1) -> bf16 [4096][4096].
// grid (16, 16), 512 thr.
__global__ __launch_bounds__(512, 2) void gemm_ffn1(
    const u16* __restrict__ A, const u16* __restrict__ Bt,
    const float* __restrict__ b1, u16* __restrict__ hb) {
  f4 acc[8][4] = {};
  gemm256_core(A, Bt, CC, acc);
  const int tid = threadIdx.x;
  const int wave = tid >> 6, lane = tid & 63;
  const int wm = wave >> 2, wn = wave & 3;
  const int lg = lane >> 4, ll = lane & 15;
#pragma unroll
  for (int j = 0; j < 4; j++) {
    const int n = blockIdx.x * 256 + wn * 64 + j * 16 + ll;
    const float bias = b1[n];
#pragma unroll
    for (int i = 0; i < 8; i++)
#pragma unroll
      for (int r = 0; r < 4; r++) {
        const int m = blockIdx.y * 256 + wm * 128 + i * 16 + lg * 4 + r;
        const float t = acc[i][j][r] + bias;
        const float g = 0.5f * t * (1.0f + erff(t * 0.70710678118654752f));
        hb[(size_t)m * FF + n] = f2bf(g);
      }
  }
}

// ------------------------------------------------------------------
// GEMM core v2 (round-5, unchanged): 128 x (NJ*32), depth-3 pipeline.
// Kept for proj (BN=64) and ffn2 (BN=64) as controls this round.
// ------------------------------------------------------------------
template<int NJ>
__device__ __forceinline__ void gemm_core(
    const u16* __restrict__ A, const u16* __restrict__ Bt, int K,
    f4 (&acc)[4][NJ]) {
  constexpr int BN = NJ * 32;
  __shared__ u16 As[3][128 * 32];
  __shared__ u16 Bs[3][BN * 32];
  const int tid = threadIdx.x;
  const int wave = tid >> 6, lane = tid & 63;
  const int wm = wave >> 1, wn = wave & 1;
  const int lg = lane >> 4, ll = lane & 15;

  const int trow = tid >> 2;
  const int tch  = (tid & 3) ^ ((trow >> 1) & 3);
  const u16* ga = A + (size_t)(blockIdx.y * 128 + trow) * K + tch * 8;
  const u16* gb = Bt + (size_t)(blockIdx.x * BN + trow) * K + tch * 8;
  const size_t g64 = (size_t)64 * K;
  const int nt = K >> 5;

  auto GSTAGE = [&](int bi, int kt) {
    u16* la = &As[bi][tid * 8];
    u16* lb = &Bs[bi][tid * 8];
    const u16* gA = ga + kt * 32;
    const u16* gB = gb + kt * 32;
    __builtin_amdgcn_global_load_lds(AS1(gA), AS3(la), 16, 0, 0);
    __builtin_amdgcn_global_load_lds(AS1(gA + g64), AS3(la + 2048), 16, 0, 0);
    __builtin_amdgcn_global_load_lds(AS1(gB), AS3(lb), 16, 0, 0);
    if constexpr (NJ == 4)
      __builtin_amdgcn_global_load_lds(AS1(gB + g64), AS3(lb + 2048), 16, 0, 0);
  };

  GSTAGE(0, 0);
  GSTAGE(1, 1);
  GSTAGE(2, 2);
  int bi = 0;
  for (int t = 0; t < nt; t++) {
    const int ahead = nt - 1 - t;
    if constexpr (NJ == 4) {
      if (ahead >= 2)      asm volatile("s_waitcnt vmcnt(8)" ::: "memory");
      else if (ahead == 1) asm volatile("s_waitcnt vmcnt(4)" ::: "memory");
      else                 asm volatile("s_waitcnt vmcnt(0)" ::: "memory");
    } else {
      if (ahead >= 2)      asm volatile("s_waitcnt vmcnt(6)" ::: "memory");
      else if (ahead == 1) asm volatile("s_waitcnt vmcnt(3)" ::: "memory");
      else                 asm volatile("s_waitcnt vmcnt(0)" ::: "memory");
    }
    __builtin_amdgcn_s_barrier();
    __builtin_amdgcn_sched_barrier(0);

    const char* as_ = (const char*)As[bi];
    const char* bs_ = (const char*)Bs[bi];
    bfrag af[4], bf[NJ];
#pragma unroll
    for (int i = 0; i < 4; i++)
      af[i] = *(const bfrag*)(as_ + swzAB((wm * 64 + i * 16 + ll) * 64 + lg * 16));
#pragma unroll
    for (int j = 0; j < NJ; j++)
      bf[j] = *(const bfrag*)(bs_ + swzAB((wn * (BN / 2) + j * 16 + ll) * 64 + lg * 16));

    __builtin_amdgcn_s_setprio(1);
#pragma unroll
    for (int i = 0; i < 4; i++)
#pragma unroll
      for (int j = 0; j < NJ; j++)
        acc[i][j] = __builtin_amdgcn_mfma_f32_16x16x32_bf16(af[i], bf[j], acc[i][j], 0, 0, 0);
    __builtin_amdgcn_s_setprio(0);

    __builtin_amdgcn_sched_barrier(0);
    __builtin_amdgcn_s_barrier();
    if (t + 3 < nt) GSTAGE(bi, t + 3);
    bi = (bi == 2) ? 0 : bi + 1;
  }
}

#define EPI_COORDS                                              \
  const int tid = threadIdx.x;                                  \
  const int wave = tid >> 6, lane = tid & 63;                   \
  const int wm = wave >> 1, wn = wave & 1;                      \
  const int lg = lane >> 4, ll = lane & 15;

// PROJ: out = x + (A @ Wp + bp) -> f32 out buffer (= d_out).  BN=64.
__global__ __launch_bounds__(256, 2) void gemm_proj(
    const u16* __restrict__ A, const u16* __restrict__ Bt,
    const float* __restrict__ bp, const float* __restrict__ x,
    float* __restrict__ outw) {
  f4 acc[4][2] = {};
  gemm_core<2>(A, Bt, CC, acc);
  EPI_COORDS
#pragma unroll
  for (int i = 0; i < 4; i++)
#pragma unroll
    for (int j = 0; j < 2; j++) {
      const int n = blockIdx.x * 64 + wn * 32 + j * 16 + ll;
      const float bias = bp[n];
#pragma unroll
      for (int r = 0; r < 4; r++) {
        const int m = blockIdx.y * 128 + wm * 64 + i * 16 + lg * 4 + r;
        const size_t idx = (size_t)m * CC + n;
        outw[idx] = acc[i][j][r] + bias + x[idx];
      }
    }
}

// FFN2: d_out = outw + (A @ W2 + b2)   (outw aliases d_out).  BN=64.
__global__ __launch_bounds__(256, 2) void gemm_ffn2(
    const u16* __restrict__ A, const u16* __restrict__ Bt,
    const float* __restrict__ b2, const float* __restrict__ outw,
    float* __restrict__ dout) {
  f4 acc[4][2] = {};
  gemm_core<2>(A, Bt, FF, acc);
  EPI_COORDS
#pragma unroll
  for (int i = 0; i < 4; i++)
#pragma unroll
    for (int j = 0; j < 2; j++) {
      const int n = blockIdx.x * 64 + wn * 32 + j * 16 + ll;
      const float bias = b2[n];
#pragma unroll
      for (int r = 0; r < 4; r++) {
        const int m = blockIdx.y * 128 + wm * 64 + i * 16 + lg * 4 + r;
        const size_t idx = (size_t)m * CC + n;
        dout[idx] = acc[i][j][r] + bias + outw[idx];
      }
    }
}

// ------------------------------------------------------------------
// Flash attention fwd, v3 (unchanged): swapped-operand QK^T, lane-local
// softmax, wave-private P, double-buffered K/V, counted vmcnt.
// ------------------------------------------------------------------
__global__ __launch_bounds__(256, 2) void attn_kernel(
    const u16* __restrict__ Q, const u16* __restrict__ Kb,
    const u16* __restrict__ Vt, u16* __restrict__ Ao) {
  __shared__ __align__(1024) u16 Ks[2][64 * 64];
  __shared__ __align__(1024) u16 Vs[2][64 * 64];
  __shared__ __align__(1024) u16 Ps[4][32 * 64];
  const int bh = blockIdx.y, qt = blockIdx.x;
  const int tid = threadIdx.x, wave = tid >> 6, lane = tid & 63;
  const int lg = lane >> 4, ll = lane & 15;

  bfrag qf[2][2];
  const u16* Qb = Q + ((size_t)bh * TT + qt * 128 + wave * 32) * HS;
#pragma unroll
  for (int qb = 0; qb < 2; qb++)
#pragma unroll
    for (int dc = 0; dc < 2; dc++)
      qf[qb][dc] = *(const bfrag*)&Qb[(qb * 16 + ll) * HS + dc * 32 + lg * 8];

  f4 o[2][4] = {};
  float mrun[2] = {-INFINITY, -INFINITY}, lrun[2] = {0.f, 0.f};

  const int trow = tid >> 3;
  const int tch  = (tid & 7) ^ (trow & 7);
  const u16* gk = Kb + ((size_t)bh * TT + trow) * HS + tch * 8;
  const u16* gv = Vt + ((size_t)bh * HS + trow) * TT + tch * 8;

  char* const pw = (char*)Ps[wave];

#define STAGE(bufi, stt)                                                          \
  do {                                                                            \
    u16* lk = &Ks[bufi][tid * 8];                                                 \
    u16* lv = &Vs[bufi][tid * 8];                                                 \
    __builtin_amdgcn_global_load_lds(AS1(gk + (size_t)(stt) * HS), AS3(lk), 16, 0, 0); \
    __builtin_amdgcn_global_load_lds(AS1(gk + (size_t)(stt) * HS + 32 * HS), AS3(lk + 2048), 16, 0, 0); \
    __builtin_amdgcn_global_load_lds(AS1(gv + (stt)), AS3(lv), 16, 0, 0);         \
    __builtin_amdgcn_global_load_lds(AS1(gv + (stt) + (size_t)32 * TT), AS3(lv + 2048), 16, 0, 0); \
  } while (0)

  STAGE(0, 0);
  int cur = 0;

  for (int st = 0; st < TT; st += 64) {
    if (st + 64 < TT) {
      STAGE(cur ^ 1, st + 64);
      asm volatile("s_waitcnt vmcnt(4)" ::: "memory");
    } else {
      asm volatile("s_waitcnt vmcnt(0)" ::: "memory");
    }
    __builtin_amdgcn_s_barrier();
    __builtin_amdgcn_sched_barrier(0);

    const char* kbuf = (const char*)Ks[cur];
    const char* vbuf = (const char*)Vs[cur];

    f4 p[2][4];
#pragma unroll
    for (int kb = 0; kb < 4; kb++) {
      const int row = kb * 16 + ll;
      const bfrag k0 = *(const bfrag*)(kbuf + swz128(row * 128 + lg * 16));
      const bfrag k1 = *(const bfrag*)(kbuf + swz128(row * 128 + 64 + lg * 16));
#pragma unroll
      for (int qb = 0; qb < 2; qb++) {
        f4 z = {0.f, 0.f, 0.f, 0.f};
        z = __builtin_amdgcn_mfma_f32_16x16x32_bf16(k0, qf[qb][0], z, 0, 0, 0);
        p[qb][kb] = __builtin_amdgcn_mfma_f32_16x16x32_bf16(k1, qf[qb][1], z, 0, 0, 0);
      }
    }

#pragma unroll
    for (int qb = 0; qb < 2; qb++) {
      float pm = p[qb][0][0];
#pragma unroll
      for (int kb = 0; kb < 4; kb++)
#pragma unroll
        for (int r = 0; r < 4; r++)
          if (kb | r) pm = fmaxf(pm, p[qb][kb][r]);
      pm = fmaxf(pm, __shfl_xor(pm, 16));
      pm = fmaxf(pm, __shfl_xor(pm, 32));
      const float mn = fmaxf(mrun[qb], pm);
      const float al = __expf(mrun[qb] - mn);
      mrun[qb] = mn;
      float rs = 0.f;
#pragma unroll
      for (int kb = 0; kb < 4; kb++)
#pragma unroll
        for (int r = 0; r < 4; r++) {
          const float e = __expf(p[qb][kb][r] - mn);
          p[qb][kb][r] = e;
          rs += e;
        }
      rs += __shfl_xor(rs, 16);
      rs += __shfl_xor(rs, 32);
      lrun[qb] = lrun[qb] * al + rs;
#pragma unroll
      for (int fo = 0; fo < 4; fo++) o[qb][fo] *= al;
#pragma unroll
      for (int kb = 0; kb < 4; kb++) {
        union { uint2 v; __bf16 h[4]; } w;
        w.h[0] = (__bf16)p[qb][kb][0];
        w.h[1] = (__bf16)p[qb][kb][1];
        w.h[2] = (__bf16)p[qb][kb][2];
        w.h[3] = (__bf16)p[qb][kb][3];
        *(uint2*)(pw + swz128((qb * 16 + ll) * 128 + kb * 32 + lg * 8)) = w.v;
      }
    }

#pragma unroll
    for (int ks = 0; ks < 2; ks++) {
      const bfrag pb0 = *(const bfrag*)(pw + swz128(ll * 128 + ks * 64 + lg * 16));
      const bfrag pb1 = *(const bfrag*)(pw + swz128((16 + ll) * 128 + ks * 64 + lg * 16));
#pragma unroll
      for (int fo = 0; fo < 4; fo++) {
        const bfrag vf = *(const bfrag*)(vbuf + swz128((fo * 16 + ll) * 128 + ks * 64 + lg * 16));
        o[0][fo] = __builtin_amdgcn_mfma_f32_16x16x32_bf16(vf, pb0, o[0][fo], 0, 0, 0);
        o[1][fo] = __builtin_amdgcn_mfma_f32_16x16x32_bf16(vf, pb1, o[1][fo], 0, 0, 0);
      }
    }

    __builtin_amdgcn_sched_barrier(0);
    __builtin_amdgcn_s_barrier();
    cur ^= 1;
  }
#undef STAGE

  const int b = bh >> 4, h = bh & 15;
#pragma unroll
  for (int qb = 0; qb < 2; qb++) {
    const float inv = 1.0f / lrun[qb];
    const int t = qt * 128 + wave * 32 + qb * 16 + ll;
#pragma unroll
    for (int fo = 0; fo < 4; fo++) {
      union { uint2 v; __bf16 h[4]; } w;
      w.h[0] = (__bf16)(o[qb][fo][0] * inv);
      w.h[1] = (__bf16)(o[qb][fo][1] * inv);
      w.h[2] = (__bf16)(o[qb][fo][2] * inv);
      w.h[3] = (__bf16)(o[qb][fo][3] * inv);
      *(uint2*)&Ao[((size_t)b * TT + t) * CC + h * HS + fo * 16 + lg * 4] = w.v;
    }
  }
}

// ------------------------------------------------------------------
extern "C" void kernel_launch(void* const* d_in, const int* in_sizes, int n_in,
                              void* d_out, int out_size, void* d_ws, size_t ws_size,
                              hipStream_t stream) {
  const float* x    = (const float*)d_in[0];
  const float* Wq   = (const float*)d_in[1];
  const float* bq   = (const float*)d_in[2];
  const float* Wk   = (const float*)d_in[3];
  const float* bk   = (const float*)d_in[4];
  const float* Wv   = (const float*)d_in[5];
  const float* bv   = (const float*)d_in[6];
  const float* Wp   = (const float*)d_in[7];
  const float* bp   = (const float*)d_in[8];
  const float* W1   = (const float*)d_in[9];
  const float* b1   = (const float*)d_in[10];
  const float* W2   = (const float*)d_in[11];
  const float* b2   = (const float*)d_in[12];
  const float* ln1w = (const float*)d_in[13];
  const float* ln1b = (const float*)d_in[14];
  const float* ln2w = (const float*)d_in[15];
  const float* ln2b = (const float*)d_in[16];
  float* dout = (float*)d_out;

  char* ws = (char*)d_ws;
  u16* wqkv = (u16*)(ws + 0);          // [3072][1024]  6.29 MB
  u16* wpt  = (u16*)(ws + 6291456);    // [1024][1024]  2.10 MB
  u16* w1t  = (u16*)(ws + 8388608);    // [4096][1024]  8.39 MB
  u16* w2t  = (u16*)(ws + 16777216);   // [1024][4096]  8.39 MB
  u16* xn   = (u16*)(ws + 25165824);   // [4096][1024]  8.39 MB (reused as LN2 out)
  u16* qb   = (u16*)(ws + 33554432);   // [32][2048][64]
  u16* kb   = (u16*)(ws + 41943040);
  u16* vb   = (u16*)(ws + 50331648);
  u16* vt   = (u16*)(ws + 58720256);   // [32][64][2048]
  u16* ao   = (u16*)(ws + 67108864);   // [4096][1024]
  u16* hb   = qb;                      // FFN hidden overlays q/k/v/vt (33.55 MB)

  dim3 blk256(256);
  dim3 blk512(512);
  dim3 blkT(32, 8);

  // weight prep: transpose to [N][K] bf16
  tr_f32_bf16<<<dim3(2, 32, 16), blkT, 0, stream>>>(Wq, wqkv,               1024,   64, 65536LL, 65536LL, 1024);
  tr_f32_bf16<<<dim3(2, 32, 16), blkT, 0, stream>>>(Wk, wqkv + 1024 * 1024, 1024,   64, 65536LL, 65536LL, 1024);
  tr_f32_bf16<<<dim3(2, 32, 16), blkT, 0, stream>>>(Wv, wqkv + 2048 * 1024, 1024,   64, 65536LL, 65536LL, 1024);
  tr_f32_bf16<<<dim3(32, 32, 1),  blkT, 0, stream>>>(Wp, wpt, 1024, 1024, 0LL, 0LL, 1024);
  tr_f32_bf16<<<dim3(128, 32, 1), blkT, 0, stream>>>(W1, w1t, 1024, 4096, 0LL, 0LL, 1024);
  tr_f32_bf16<<<dim3(32, 128, 1), blkT, 0, stream>>>(W2, w2t, 4096, 1024, 0LL, 0LL, 4096);

  // LN1 -> xn (bf16)
  ln_kernel<<<dim3(MT), blk256, 0, stream>>>(x, ln1w, ln1b, xn);

  // QKV projection (q pre-scaled by C^-0.5) — 256^2 phased core
  gemm_qkv<<<dim3(12, 16), blk512, 0, stream>>>(xn, wqkv, bq, bk, bv, qb, kb, vb);

  // V -> Vt [bh][64][2048]
  tr_bf16<<<dim3(2, 64, 32), blkT, 0, stream>>>(vb, vt, 2048, 64, 131072LL, 131072LL, 2048);

  // attention
  attn_kernel<<<dim3(16, 32), blk256, 0, stream>>>(qb, kb, vt, ao);

  // out = x + ao @ Wp + bp   (f32, into d_out)   BN=64 -> 512 blocks
  gemm_proj<<<dim3(16, 32), blk256, 0, stream>>>(ao, wpt, bp, x, dout);

  // LN2 -> xn (reuse)
  ln_kernel<<<dim3(MT), blk256, 0, stream>>>(dout, ln2w, ln2b, xn);

  // FFN — ffn1 on 256^2 phased core, ffn2 unchanged (control)
  gemm_ffn1<<<dim3(16, 16), blk512, 0, stream>>>(xn, w1t, b1, hb);
  gemm_ffn2<<<dim3(16, 32), blk256, 0, stream>>>(hb, w2t, b2, dout, dout);
}

// Round 7
// 279.552 us; speedup vs baseline: 1.0742x; 1.0742x over previous
//
#include <hip/hip_runtime.h>
#include <math.h>

// ---- problem dims (B=2, T=2048, C=1024, H=16, HS=64) ----
#define BB 2
#define TT 2048
#define CC 1024
#define HH 16
#define HS 64
#define MT 4096   // B*T
#define FF 4096   // 4*C

typedef unsigned short u16;
typedef __bf16 bfrag __attribute__((ext_vector_type(8)));
typedef float f4 __attribute__((ext_vector_type(4)));

#define AS1(p) ((const __attribute__((address_space(1))) void*)(p))
#define AS3(p) ((__attribute__((address_space(3))) void*)(p))

__device__ __forceinline__ u16 f2bf(float f) {
  union { float f; unsigned u; } a; a.f = f;
  return (u16)((a.u + 0x7fffu + ((a.u >> 16) & 1u)) >> 16);
}
__device__ __forceinline__ float bf2f(u16 u) {
  union { unsigned u; float f; } a; a.u = ((unsigned)u) << 16; return a.f;
}

// XOR-swizzle for 128-byte-row LDS tiles (attention)
__device__ __forceinline__ int swz128(int byteoff) {
  return byteoff ^ (((byteoff >> 7) & 7) << 4);
}
// XOR-swizzle for 64-byte-row LDS tiles (GEMM A/B)
__device__ __forceinline__ int swzAB(int byteoff) {
  return byteoff ^ (((byteoff >> 7) & 3) << 4);
}

// XCD-aware chunked swizzle (T1): hardware block o (dispatched round-robin
// o%8 -> XCD) computes tile (o%8)*q + o/8 so each XCD owns a contiguous
// tile range.  Requires nwg % 8 == 0 (all our GEMM grids satisfy this).
#define XCD_SWZ_2D(BX, BY)                                                     \
  int _fl = (int)blockIdx.y * gridDim.x + blockIdx.x;                          \
  const int _nw = gridDim.x * gridDim.y;                                       \
  _fl = (_fl & 7) * (_nw >> 3) + (_fl >> 3);                                   \
  const int BX = _fl % gridDim.x;                                              \
  const int BY = _fl / gridDim.x;

// ------------------------------------------------------------------
// Tiled transpose f32 -> bf16.
// ------------------------------------------------------------------
__global__ void tr_f32_bf16(const float* __restrict__ src, u16* __restrict__ dst,
                            int R, int Cc, long long sb, long long db, int dld) {
  __shared__ float t[32][33];
  const int bz = blockIdx.z;
  const int r0 = blockIdx.y * 32, c0 = blockIdx.x * 32;
  const int tx = threadIdx.x, ty = threadIdx.y;
  const float* s = src + bz * sb;
  u16* d = dst + bz * db;
#pragma unroll
  for (int i = 0; i < 4; i++)
    t[ty + i * 8][tx] = s[(size_t)(r0 + ty + i * 8) * Cc + c0 + tx];
  __syncthreads();
#pragma unroll
  for (int i = 0; i < 4; i++)
    d[(size_t)(c0 + ty + i * 8) * dld + r0 + tx] = f2bf(t[tx][ty + i * 8]);
}

// bf16 -> bf16 transpose (for V)
__global__ void tr_bf16(const u16* __restrict__ src, u16* __restrict__ dst,
                        int R, int Cc, long long sb, long long db, int dld) {
  __shared__ u16 t[32][33];
  const int bz = blockIdx.z;
  const int r0 = blockIdx.y * 32, c0 = blockIdx.x * 32;
  const int tx = threadIdx.x, ty = threadIdx.y;
  const u16* s = src + bz * sb;
  u16* d = dst + bz * db;
#pragma unroll
  for (int i = 0; i < 4; i++)
    t[ty + i * 8][tx] = s[(size_t)(r0 + ty + i * 8) * Cc + c0 + tx];
  __syncthreads();
#pragma unroll
  for (int i = 0; i < 4; i++)
    d[(size_t)(c0 + ty + i * 8) * dld + r0 + tx] = t[tx][ty + i * 8];
}

// ------------------------------------------------------------------
// LayerNorm: one block (256 thr) per row of [4096][1024] f32 -> bf16
// ------------------------------------------------------------------
__global__ __launch_bounds__(256) void ln_kernel(
    const float* __restrict__ x, const float* __restrict__ w,
    const float* __restrict__ b, u16* __restrict__ y) {
  const int row = blockIdx.x, tid = threadIdx.x;
  const float4 v = reinterpret_cast<const float4*>(x + (size_t)row * CC)[tid];
  float s = v.x + v.y + v.z + v.w;
  float s2 = v.x * v.x + v.y * v.y + v.z * v.z + v.w * v.w;
#pragma unroll
  for (int off = 32; off >= 1; off >>= 1) {
    s += __shfl_xor(s, off);
    s2 += __shfl_xor(s2, off);
  }
  __shared__ float ps[4], ps2[4];
  const int wave = tid >> 6, lane = tid & 63;
  if (lane == 0) { ps[wave] = s; ps2[wave] = s2; }
  __syncthreads();
  s = ps[0] + ps[1] + ps[2] + ps[3];
  s2 = ps2[0] + ps2[1] + ps2[2] + ps2[3];
  const float mu = s * (1.f / CC);
  const float rstd = rsqrtf(s2 * (1.f / CC) - mu * mu + 1e-5f);
  const float4 wv = reinterpret_cast<const float4*>(w)[tid];
  const float4 bv = reinterpret_cast<const float4*>(b)[tid];
  ushort4 o;
  o.x = f2bf((v.x - mu) * rstd * wv.x + bv.x);
  o.y = f2bf((v.y - mu) * rstd * wv.y + bv.y);
  o.z = f2bf((v.z - mu) * rstd * wv.z + bv.z);
  o.w = f2bf((v.w - mu) * rstd * wv.w + bv.w);
  reinterpret_cast<ushort4*>(y + (size_t)row * CC)[tid] = o;
}

// ------------------------------------------------------------------
// GEMM core (depth-3 pipeline, round-5-proven): 128 x (NJ*32) tile.
// 3 LDS buffers, raw barriers, counted vmcnt, XOR-swizzle both-sides,
// setprio around MFMA.  A [M][lda], Bt [N][ldb] row-major bf16,
// K iterated in 32-col steps.  256 thr = 4 waves (2x2).
// smem layout: A bufs 3*4096 u16, then B bufs 3*(BN*32) u16.
// ------------------------------------------------------------------
template<int NJ>  // 4 -> BN=128 (4 loads/stage), 2 -> BN=64 (3 loads/stage)
__device__ __forceinline__ void gemm_core(
    u16* smem, const u16* __restrict__ A, const u16* __restrict__ Bt,
    int K, int lda, int ldb, int bmi, int bni, f4 (&acc)[4][NJ]) {
  constexpr int BN = NJ * 32;
  constexpr int BBUF = BN * 32;
  u16* As = smem;                 // 3 * 4096
  u16* Bs = smem + 3 * 4096;      // 3 * BBUF
  const int tid = threadIdx.x;
  const int wave = tid >> 6, lane = tid & 63;
  const int wm = wave >> 1, wn = wave & 1;
  const int lg = lane >> 4, ll = lane & 15;

  const int trow = tid >> 2;
  const int tch  = (tid & 3) ^ ((trow >> 1) & 3);
  const u16* ga = A + (size_t)(bmi * 128 + trow) * lda + tch * 8;
  const u16* gb = Bt + (size_t)(bni * BN + trow) * ldb + tch * 8;
  const size_t g64a = (size_t)64 * lda;
  const size_t g64b = (size_t)64 * ldb;
  const int nt = K >> 5;

  auto GSTAGE = [&](int bi, int kt) {
    u16* la = &As[bi * 4096 + tid * 8];
    u16* lb = &Bs[bi * BBUF + tid * 8];
    const u16* gA = ga + kt * 32;
    const u16* gB = gb + kt * 32;
    __builtin_amdgcn_global_load_lds(AS1(gA), AS3(la), 16, 0, 0);
    __builtin_amdgcn_global_load_lds(AS1(gA + g64a), AS3(la + 2048), 16, 0, 0);
    __builtin_amdgcn_global_load_lds(AS1(gB), AS3(lb), 16, 0, 0);
    if constexpr (NJ == 4)
      __builtin_amdgcn_global_load_lds(AS1(gB + g64b), AS3(lb + 2048), 16, 0, 0);
  };

  GSTAGE(0, 0);
  GSTAGE(1, 1);
  GSTAGE(2, 2);
  int bi = 0;
  for (int t = 0; t < nt; t++) {
    const int ahead = nt - 1 - t;
    if constexpr (NJ == 4) {
      if (ahead >= 2)      asm volatile("s_waitcnt vmcnt(8)" ::: "memory");
      else if (ahead == 1) asm volatile("s_waitcnt vmcnt(4)" ::: "memory");
      else                 asm volatile("s_waitcnt vmcnt(0)" ::: "memory");
    } else {
      if (ahead >= 2)      asm volatile("s_waitcnt vmcnt(6)" ::: "memory");
      else if (ahead == 1) asm volatile("s_waitcnt vmcnt(3)" ::: "memory");
      else                 asm volatile("s_waitcnt vmcnt(0)" ::: "memory");
    }
    __builtin_amdgcn_s_barrier();
    __builtin_amdgcn_sched_barrier(0);

    const char* as_ = (const char*)(As + bi * 4096);
    const char* bs_ = (const char*)(Bs + bi * BBUF);
    bfrag af[4], bf[NJ];
#pragma unroll
    for (int i = 0; i < 4; i++)
      af[i] = *(const bfrag*)(as_ + swzAB((wm * 64 + i * 16 + ll) * 64 + lg * 16));
#pragma unroll
    for (int j = 0; j < NJ; j++)
      bf[j] = *(const bfrag*)(bs_ + swzAB((wn * (BN / 2) + j * 16 + ll) * 64 + lg * 16));

    __builtin_amdgcn_s_setprio(1);
#pragma unroll
    for (int i = 0; i < 4; i++)
#pragma unroll
      for (int j = 0; j < NJ; j++)
        acc[i][j] = __builtin_amdgcn_mfma_f32_16x16x32_bf16(af[i], bf[j], acc[i][j], 0, 0, 0);
    __builtin_amdgcn_s_setprio(0);

    __builtin_amdgcn_sched_barrier(0);
    __builtin_amdgcn_s_barrier();
    if (t + 3 < nt) GSTAGE(bi, t + 3);
    bi = (bi == 2) ? 0 : bi + 1;
  }
}

// C/D frag mapping: col = lane&15, row = (lane>>4)*4 + r  (verified m89)
#define EPI_COORDS                                              \
  const int tid = threadIdx.x;                                  \
  const int wave = tid >> 6, lane = tid & 63;                   \
  const int wm = wave >> 1, wn = wave & 1;                      \
  const int lg = lane >> 4, ll = lane & 15;

// QKV: N=3072 (q|k|v), bias add, fold C^-0.5*log2e into q, LDS-staged
// coalesced scatter to [BH][T][HS].  grid (24,32), NJ=4.
__global__ __launch_bounds__(256, 3) void gemm_qkv(
    const u16* __restrict__ A, const u16* __restrict__ Bt,
    const float* __restrict__ bq, const float* __restrict__ bk,
    const float* __restrict__ bv,
    u16* __restrict__ q, u16* __restrict__ k, u16* __restrict__ v) {
  __shared__ u16 smem[24576];
  XCD_SWZ_2D(bx, by)
  f4 acc[4][4] = {};
  gemm_core<4>(smem, A, Bt, CC, CC, CC, by, bx, acc);
  EPI_COORDS
  __syncthreads();
  // stage (bias+scale applied here); q also pre-scaled by log2(e) for exp2 attn
#pragma unroll
  for (int j = 0; j < 4; j++) {
    const int n = bx * 128 + wn * 64 + j * 16 + ll;
    const int sec = n >> 10, nn = n & 1023;
    const float bias = (sec == 0 ? bq : (sec == 1 ? bk : bv))[nn];
    const float scale = (sec == 0) ? 0.045084220027780106f : 1.0f;
#pragma unroll
    for (int i = 0; i < 4; i++)
#pragma unroll
      for (int r = 0; r < 4; r++)
        smem[(wm * 64 + i * 16 + lg * 4 + r) * 136 + wn * 64 + j * 16 + ll] =
            f2bf((acc[i][j][r] + bias) * scale);
  }
  __syncthreads();
  const int rr = tid >> 4, cb = (tid & 15) * 8;
#pragma unroll
  for (int R = 0; R < 8; R++) {
    const int row = R * 16 + rr;
    const int m = by * 128 + row, b = m >> 11, t = m & 2047;
    const int n = bx * 128 + cb;
    const int sec = n >> 10, nn = n & 1023, h = nn >> 6, d = nn & 63;
    u16* dst = sec == 0 ? q : (sec == 1 ? k : v);
    *(uint4*)&dst[(((size_t)b * HH + h) * TT + t) * HS + d] =
        *(const uint4*)&smem[row * 136 + cb];
  }
}

// FFN1: h = gelu_exact(A @ W1 + b1) -> bf16 [4096][4096], LDS-staged
// coalesced writeback.  grid (32,32), NJ=4.
__global__ __launch_bounds__(256, 3) void gemm_ffn1(
    const u16* __restrict__ A, const u16* __restrict__ Bt,
    const float* __restrict__ b1, u16* __restrict__ hb) {
  __shared__ u16 smem[24576];
  XCD_SWZ_2D(bx, by)
  f4 acc[4][4] = {};
  gemm_core<4>(smem, A, Bt, CC, CC, CC, by, bx, acc);
  EPI_COORDS
  __syncthreads();
#pragma unroll
  for (int j = 0; j < 4; j++) {
    const int n = bx * 128 + wn * 64 + j * 16 + ll;
    const float bias = b1[n];
#pragma unroll
    for (int i = 0; i < 4; i++)
#pragma unroll
      for (int r = 0; r < 4; r++) {
        const float t = acc[i][j][r] + bias;
        const float g = 0.5f * t * (1.0f + erff(t * 0.70710678118654752f));
        smem[(wm * 64 + i * 16 + lg * 4 + r) * 136 + wn * 64 + j * 16 + ll] = f2bf(g);
      }
  }
  __syncthreads();
  const int rr = tid >> 4, cb = (tid & 15) * 8;
#pragma unroll
  for (int R = 0; R < 8; R++) {
    const int row = R * 16 + rr;
    *(uint4*)&hb[(size_t)(by * 128 + row) * FF + bx * 128 + cb] =
        *(const uint4*)&smem[row * 136 + cb];
  }
}

// FFN2 split-K chunk GEMM: partial = A[:, z*2048:(z+1)*2048] @ W2-chunk,
// bf16 partials to p0/p1 (dead weight-prep workspace).  grid (8,32,2), NJ=4.
__global__ __launch_bounds__(256, 3) void gemm_ffn2sk(
    const u16* __restrict__ A, const u16* __restrict__ Bt,
    u16* __restrict__ p0, u16* __restrict__ p1) {
  __shared__ u16 smem[24576];
  // 3D chunked XCD swizzle (nwg = 512, %8==0)
  int _fl = ((int)blockIdx.z * gridDim.y + blockIdx.y) * gridDim.x + blockIdx.x;
  const int _nw = gridDim.x * gridDim.y * gridDim.z;
  _fl = (_fl & 7) * (_nw >> 3) + (_fl >> 3);
  const int bx = _fl % gridDim.x;
  const int by = (_fl / gridDim.x) % gridDim.y;
  const int bz = _fl / (gridDim.x * gridDim.y);

  f4 acc[4][4] = {};
  gemm_core<4>(smem, A + bz * 2048, Bt + bz * 2048, 2048, FF, FF, by, bx, acc);
  EPI_COORDS
  __syncthreads();
#pragma unroll
  for (int j = 0; j < 4; j++)
#pragma unroll
    for (int i = 0; i < 4; i++)
#pragma unroll
      for (int r = 0; r < 4; r++)
        smem[(wm * 64 + i * 16 + lg * 4 + r) * 136 + wn * 64 + j * 16 + ll] =
            f2bf(acc[i][j][r]);
  __syncthreads();
  u16* pp = bz ? p1 : p0;
  const int rr = tid >> 4, cb = (tid & 15) * 8;
#pragma unroll
  for (int R = 0; R < 8; R++) {
    const int row = R * 16 + rr;
    *(uint4*)&pp[(size_t)(by * 128 + row) * CC + bx * 128 + cb] =
        *(const uint4*)&smem[row * 136 + cb];
  }
}

// FFN2 reduce: dout = dout(residual) + b2 + p0 + p1.  8 elems/thread.
__global__ __launch_bounds__(256) void ffn2_reduce(
    const u16* __restrict__ p0, const u16* __restrict__ p1,
    const float* __restrict__ b2, float* __restrict__ dout) {
  const int gid = blockIdx.x * 256 + threadIdx.x;
  const int n0 = (gid * 8) & (CC - 1);
  const uint4 a = ((const uint4*)p0)[gid];
  const uint4 c = ((const uint4*)p1)[gid];
  const u16* au = (const u16*)&a;
  const u16* cu = (const u16*)&c;
  float4 d0 = ((const float4*)dout)[gid * 2];
  float4 d1 = ((const float4*)dout)[gid * 2 + 1];
  const float4 w0 = *(const float4*)&b2[n0];
  const float4 w1 = *(const float4*)&b2[n0 + 4];
  d0.x += w0.x + bf2f(au[0]) + bf2f(cu[0]);
  d0.y += w0.y + bf2f(au[1]) + bf2f(cu[1]);
  d0.z += w0.z + bf2f(au[2]) + bf2f(cu[2]);
  d0.w += w0.w + bf2f(au[3]) + bf2f(cu[3]);
  d1.x += w1.x + bf2f(au[4]) + bf2f(cu[4]);
  d1.y += w1.y + bf2f(au[5]) + bf2f(cu[5]);
  d1.z += w1.z + bf2f(au[6]) + bf2f(cu[6]);
  d1.w += w1.w + bf2f(au[7]) + bf2f(cu[7]);
  ((float4*)dout)[gid * 2] = d0;
  ((float4*)dout)[gid * 2 + 1] = d1;
}

// PROJ: out = x + (A @ Wp + bp) -> f32 (= d_out).  BN=64, NJ=2, grid (16,32).
__global__ __launch_bounds__(256, 3) void gemm_proj(
    const u16* __restrict__ A, const u16* __restrict__ Bt,
    const float* __restrict__ bp, const float* __restrict__ x,
    float* __restrict__ outw) {
  __shared__ u16 smem[18432];
  XCD_SWZ_2D(bx, by)
  f4 acc[4][2] = {};
  gemm_core<2>(smem, A, Bt, CC, CC, CC, by, bx, acc);
  EPI_COORDS
#pragma unroll
  for (int i = 0; i < 4; i++)
#pragma unroll
    for (int j = 0; j < 2; j++) {
      const int n = bx * 64 + wn * 32 + j * 16 + ll;
      const float bias = bp[n];
#pragma unroll
      for (int r = 0; r < 4; r++) {
        const int m = by * 128 + wm * 64 + i * 16 + lg * 4 + r;
        const size_t idx = (size_t)m * CC + n;
        outw[idx] = acc[i][j][r] + bias + x[idx];
      }
    }
}

// ------------------------------------------------------------------
// Flash attention fwd (round-3-proven structure; exp -> exp2 domain:
// Q pre-scaled by C^-0.5 * log2e in gemm_qkv).
// ------------------------------------------------------------------
__global__ __launch_bounds__(256, 2) void attn_kernel(
    const u16* __restrict__ Q, const u16* __restrict__ Kb,
    const u16* __restrict__ Vt, u16* __restrict__ Ao) {
  __shared__ __align__(1024) u16 Ks[2][64 * 64];
  __shared__ __align__(1024) u16 Vs[2][64 * 64];
  __shared__ __align__(1024) u16 Ps[4][32 * 64];
  const int bh = blockIdx.y, qt = blockIdx.x;
  const int tid = threadIdx.x, wave = tid >> 6, lane = tid & 63;
  const int lg = lane >> 4, ll = lane & 15;

  bfrag qf[2][2];
  const u16* Qb = Q + ((size_t)bh * TT + qt * 128 + wave * 32) * HS;
#pragma unroll
  for (int qb = 0; qb < 2; qb++)
#pragma unroll
    for (int dc = 0; dc < 2; dc++)
      qf[qb][dc] = *(const bfrag*)&Qb[(qb * 16 + ll) * HS + dc * 32 + lg * 8];

  f4 o[2][4] = {};
  float mrun[2] = {-INFINITY, -INFINITY}, lrun[2] = {0.f, 0.f};

  const int trow = tid >> 3;
  const int tch  = (tid & 7) ^ (trow & 7);
  const u16* gk = Kb + ((size_t)bh * TT + trow) * HS + tch * 8;
  const u16* gv = Vt + ((size_t)bh * HS + trow) * TT + tch * 8;

  char* const pw = (char*)Ps[wave];

#define STAGE(bufi, stt)                                                          \
  do {                                                                            \
    u16* lk = &Ks[bufi][tid * 8];                                                 \
    u16* lv = &Vs[bufi][tid * 8];                                                 \
    __builtin_amdgcn_global_load_lds(AS1(gk + (size_t)(stt) * HS), AS3(lk), 16, 0, 0); \
    __builtin_amdgcn_global_load_lds(AS1(gk + (size_t)(stt) * HS + 32 * HS), AS3(lk + 2048), 16, 0, 0); \
    __builtin_amdgcn_global_load_lds(AS1(gv + (stt)), AS3(lv), 16, 0, 0);         \
    __builtin_amdgcn_global_load_lds(AS1(gv + (stt) + (size_t)32 * TT), AS3(lv + 2048), 16, 0, 0); \
  } while (0)

  STAGE(0, 0);
  int cur = 0;

  for (int st = 0; st < TT; st += 64) {
    if (st + 64 < TT) {
      STAGE(cur ^ 1, st + 64);
      asm volatile("s_waitcnt vmcnt(4)" ::: "memory");
    } else {
      asm volatile("s_waitcnt vmcnt(0)" ::: "memory");
    }
    __builtin_amdgcn_s_barrier();
    __builtin_amdgcn_sched_barrier(0);

    const char* kbuf = (const char*)Ks[cur];
    const char* vbuf = (const char*)Vs[cur];

    f4 p[2][4];
#pragma unroll
    for (int kb = 0; kb < 4; kb++) {
      const int row = kb * 16 + ll;
      const bfrag k0 = *(const bfrag*)(kbuf + swz128(row * 128 + lg * 16));
      const bfrag k1 = *(const bfrag*)(kbuf + swz128(row * 128 + 64 + lg * 16));
#pragma unroll
      for (int qb = 0; qb < 2; qb++) {
        f4 z = {0.f, 0.f, 0.f, 0.f};
        z = __builtin_amdgcn_mfma_f32_16x16x32_bf16(k0, qf[qb][0], z, 0, 0, 0);
        p[qb][kb] = __builtin_amdgcn_mfma_f32_16x16x32_bf16(k1, qf[qb][1], z, 0, 0, 0);
      }
    }

#pragma unroll
    for (int qb = 0; qb < 2; qb++) {
      float pm = p[qb][0][0];
#pragma unroll
      for (int kb = 0; kb < 4; kb++)
#pragma unroll
        for (int r = 0; r < 4; r++)
          if (kb | r) pm = fmaxf(pm, p[qb][kb][r]);
      pm = fmaxf(pm, __shfl_xor(pm, 16));
      pm = fmaxf(pm, __shfl_xor(pm, 32));
      const float mn = fmaxf(mrun[qb], pm);
      const float al = exp2f(mrun[qb] - mn);
      mrun[qb] = mn;
      float rs = 0.f;
#pragma unroll
      for (int kb = 0; kb < 4; kb++)
#pragma unroll
        for (int r = 0; r < 4; r++) {
          const float e = exp2f(p[qb][kb][r] - mn);
          p[qb][kb][r] = e;
          rs += e;
        }
      rs += __shfl_xor(rs, 16);
      rs += __shfl_xor(rs, 32);
      lrun[qb] = lrun[qb] * al + rs;
#pragma unroll
      for (int fo = 0; fo < 4; fo++) o[qb][fo] *= al;
#pragma unroll
      for (int kb = 0; kb < 4; kb++) {
        union { uint2 v; __bf16 h[4]; } w;
        w.h[0] = (__bf16)p[qb][kb][0];
        w.h[1] = (__bf16)p[qb][kb][1];
        w.h[2] = (__bf16)p[qb][kb][2];
        w.h[3] = (__bf16)p[qb][kb][3];
        *(uint2*)(pw + swz128((qb * 16 + ll) * 128 + kb * 32 + lg * 8)) = w.v;
      }
    }

#pragma unroll
    for (int ks = 0; ks < 2; ks++) {
      const bfrag pb0 = *(const bfrag*)(pw + swz128(ll * 128 + ks * 64 + lg * 16));
      const bfrag pb1 = *(const bfrag*)(pw + swz128((16 + ll) * 128 + ks * 64 + lg * 16));
#pragma unroll
      for (int fo = 0; fo < 4; fo++) {
        const bfrag vf = *(const bfrag*)(vbuf + swz128((fo * 16 + ll) * 128 + ks * 64 + lg * 16));
        o[0][fo] = __builtin_amdgcn_mfma_f32_16x16x32_bf16(vf, pb0, o[0][fo], 0, 0, 0);
        o[1][fo] = __builtin_amdgcn_mfma_f32_16x16x32_bf16(vf, pb1, o[1][fo], 0, 0, 0);
      }
    }

    __builtin_amdgcn_sched_barrier(0);
    __builtin_amdgcn_s_barrier();
    cur ^= 1;
  }
#undef STAGE

  const int b = bh >> 4, h = bh & 15;
#pragma unroll
  for (int qb = 0; qb < 2; qb++) {
    const float inv = 1.0f / lrun[qb];
    const int t = qt * 128 + wave * 32 + qb * 16 + ll;
#pragma unroll
    for (int fo = 0; fo < 4; fo++) {
      union { uint2 v; __bf16 h[4]; } w;
      w.h[0] = (__bf16)(o[qb][fo][0] * inv);
      w.h[1] = (__bf16)(o[qb][fo][1] * inv);
      w.h[2] = (__bf16)(o[qb][fo][2] * inv);
      w.h[3] = (__bf16)(o[qb][fo][3] * inv);
      *(uint2*)&Ao[((size_t)b * TT + t) * CC + h * HS + fo * 16 + lg * 4] = w.v;
    }
  }
}

// ------------------------------------------------------------------
extern "C" void kernel_launch(void* const* d_in, const int* in_sizes, int n_in,
                              void* d_out, int out_size, void* d_ws, size_t ws_size,
                              hipStream_t stream) {
  const float* x    = (const float*)d_in[0];
  const float* Wq   = (const float*)d_in[1];
  const float* bq   = (const float*)d_in[2];
  const float* Wk   = (const float*)d_in[3];
  const float* bk   = (const float*)d_in[4];
  const float* Wv   = (const float*)d_in[5];
  const float* bv   = (const float*)d_in[6];
  const float* Wp   = (const float*)d_in[7];
  const float* bp   = (const float*)d_in[8];
  const float* W1   = (const float*)d_in[9];
  const float* b1   = (const float*)d_in[10];
  const float* W2   = (const float*)d_in[11];
  const float* b2   = (const float*)d_in[12];
  const float* ln1w = (const float*)d_in[13];
  const float* ln1b = (const float*)d_in[14];
  const float* ln2w = (const float*)d_in[15];
  const float* ln2b = (const float*)d_in[16];
  float* dout = (float*)d_out;

  char* ws = (char*)d_ws;
  u16* wqkv = (u16*)(ws + 0);          // [3072][1024]  6.29 MB (dead after qkv)
  u16* wpt  = (u16*)(ws + 6291456);    // [1024][1024]  2.10 MB (dead after proj)
  u16* w1t  = (u16*)(ws + 8388608);    // [4096][1024]  8.39 MB (dead after ffn1)
  u16* w2t  = (u16*)(ws + 16777216);   // [1024][4096]  8.39 MB
  u16* xn   = (u16*)(ws + 25165824);   // [4096][1024]  8.39 MB (reused for LN2)
  u16* qb   = (u16*)(ws + 33554432);   // [32][2048][64]
  u16* kb   = (u16*)(ws + 41943040);
  u16* vb   = (u16*)(ws + 50331648);
  u16* vt   = (u16*)(ws + 58720256);   // [32][64][2048]
  u16* ao   = (u16*)(ws + 67108864);   // [4096][1024]
  u16* hb   = qb;                      // FFN hidden overlays q/k/v/vt (33.55 MB)
  // ffn2 split-K partials overlay dead weight buffers:
  u16* pk0  = (u16*)(ws + 0);          // [4096][1024] bf16 over wqkv+wpt
  u16* pk1  = (u16*)(ws + 8388608);    // [4096][1024] bf16 over w1t

  dim3 blk256(256);
  dim3 blkT(32, 8);

  // weight prep: transpose to [N][K] bf16
  tr_f32_bf16<<<dim3(2, 32, 16), blkT, 0, stream>>>(Wq, wqkv,               1024,   64, 65536LL, 65536LL, 1024);
  tr_f32_bf16<<<dim3(2, 32, 16), blkT, 0, stream>>>(Wk, wqkv + 1024 * 1024, 1024,   64, 65536LL, 65536LL, 1024);
  tr_f32_bf16<<<dim3(2, 32, 16), blkT, 0, stream>>>(Wv, wqkv + 2048 * 1024, 1024,   64, 65536LL, 65536LL, 1024);
  tr_f32_bf16<<<dim3(32, 32, 1),  blkT, 0, stream>>>(Wp, wpt, 1024, 1024, 0LL, 0LL, 1024);
  tr_f32_bf16<<<dim3(128, 32, 1), blkT, 0, stream>>>(W1, w1t, 1024, 4096, 0LL, 0LL, 1024);
  tr_f32_bf16<<<dim3(32, 128, 1), blkT, 0, stream>>>(W2, w2t, 4096, 1024, 0LL, 0LL, 4096);

  // LN1 -> xn (bf16)
  ln_kernel<<<dim3(MT), blk256, 0, stream>>>(x, ln1w, ln1b, xn);

  // QKV projection (q pre-scaled by C^-0.5 * log2e)
  gemm_qkv<<<dim3(24, 32), blk256, 0, stream>>>(xn, wqkv, bq, bk, bv, qb, kb, vb);

  // V -> Vt [bh][64][2048]
  tr_bf16<<<dim3(2, 64, 32), blkT, 0, stream>>>(vb, vt, 2048, 64, 131072LL, 131072LL, 2048);

  // attention
  attn_kernel<<<dim3(16, 32), blk256, 0, stream>>>(qb, kb, vt, ao);

  // out = x + ao @ Wp + bp   (f32, into d_out)
  gemm_proj<<<dim3(16, 32), blk256, 0, stream>>>(ao, wpt, bp, x, dout);

  // LN2 -> xn (reuse)
  ln_kernel<<<dim3(MT), blk256, 0, stream>>>(dout, ln2w, ln2b, xn);

  // FFN
  gemm_ffn1<<<dim3(32, 32), blk256, 0, stream>>>(xn, w1t, b1, hb);
  gemm_ffn2sk<<<dim3(8, 32, 2), blk256, 0, stream>>>(hb, w2t, pk0, pk1);
  ffn2_reduce<<<dim3(MT * CC / 8 / 256), blk256, 0, stream>>>(pk0, pk1, b2, dout);
}

// Round 8
// 277.494 us; speedup vs baseline: 1.0821x; 1.0074x over previous
//
#include <hip/hip_runtime.h>
#include <math.h>

// ---- problem dims (B=2, T=2048, C=1024, H=16, HS=64) ----
#define BB 2
#define TT 2048
#define CC 1024
#define HH 16
#define HS 64
#define MT 4096   // B*T
#define FF 4096   // 4*C

typedef unsigned short u16;
typedef __bf16 bfrag __attribute__((ext_vector_type(8)));
typedef float f4 __attribute__((ext_vector_type(4)));

#define AS1(p) ((const __attribute__((address_space(1))) void*)(p))
#define AS3(p) ((__attribute__((address_space(3))) void*)(p))

__device__ __forceinline__ u16 f2bf(float f) {
  union { float f; unsigned u; } a; a.f = f;
  return (u16)((a.u + 0x7fffu + ((a.u >> 16) & 1u)) >> 16);
}
__device__ __forceinline__ float bf2f(u16 u) {
  union { unsigned u; float f; } a; a.u = ((unsigned)u) << 16; return a.f;
}

// XOR-swizzle for 128-byte-row LDS tiles (attention)
__device__ __forceinline__ int swz128(int byteoff) {
  return byteoff ^ (((byteoff >> 7) & 7) << 4);
}
// XOR-swizzle for 64-byte-row LDS tiles (GEMM A/B)
__device__ __forceinline__ int swzAB(int byteoff) {
  return byteoff ^ (((byteoff >> 7) & 3) << 4);
}

// XCD-aware chunked swizzle (T1).  Requires nwg % 8 == 0.
#define XCD_SWZ_2D(BX, BY)                                                     \
  int _fl = (int)blockIdx.y * gridDim.x + blockIdx.x;                          \
  const int _nw = gridDim.x * gridDim.y;                                       \
  _fl = (_fl & 7) * (_nw >> 3) + (_fl >> 3);                                   \
  const int BX = _fl % gridDim.x;                                              \
  const int BY = _fl / gridDim.x;

// ------------------------------------------------------------------
// Tiled transpose f32 -> bf16.
// ------------------------------------------------------------------
__global__ void tr_f32_bf16(const float* __restrict__ src, u16* __restrict__ dst,
                            int R, int Cc, long long sb, long long db, int dld) {
  __shared__ float t[32][33];
  const int bz = blockIdx.z;
  const int r0 = blockIdx.y * 32, c0 = blockIdx.x * 32;
  const int tx = threadIdx.x, ty = threadIdx.y;
  const float* s = src + bz * sb;
  u16* d = dst + bz * db;
#pragma unroll
  for (int i = 0; i < 4; i++)
    t[ty + i * 8][tx] = s[(size_t)(r0 + ty + i * 8) * Cc + c0 + tx];
  __syncthreads();
#pragma unroll
  for (int i = 0; i < 4; i++)
    d[(size_t)(c0 + ty + i * 8) * dld + r0 + tx] = f2bf(t[tx][ty + i * 8]);
}

// bf16 -> bf16 transpose (for V)
__global__ void tr_bf16(const u16* __restrict__ src, u16* __restrict__ dst,
                        int R, int Cc, long long sb, long long db, int dld) {
  __shared__ u16 t[32][33];
  const int bz = blockIdx.z;
  const int r0 = blockIdx.y * 32, c0 = blockIdx.x * 32;
  const int tx = threadIdx.x, ty = threadIdx.y;
  const u16* s = src + bz * sb;
  u16* d = dst + bz * db;
#pragma unroll
  for (int i = 0; i < 4; i++)
    t[ty + i * 8][tx] = s[(size_t)(r0 + ty + i * 8) * Cc + c0 + tx];
  __syncthreads();
#pragma unroll
  for (int i = 0; i < 4; i++)
    d[(size_t)(c0 + ty + i * 8) * dld + r0 + tx] = t[tx][ty + i * 8];
}

// ------------------------------------------------------------------
// LayerNorm: one block (256 thr) per row of [4096][1024] f32 -> bf16
// ------------------------------------------------------------------
__global__ __launch_bounds__(256) void ln_kernel(
    const float* __restrict__ x, const float* __restrict__ w,
    const float* __restrict__ b, u16* __restrict__ y) {
  const int row = blockIdx.x, tid = threadIdx.x;
  const float4 v = reinterpret_cast<const float4*>(x + (size_t)row * CC)[tid];
  float s = v.x + v.y + v.z + v.w;
  float s2 = v.x * v.x + v.y * v.y + v.z * v.z + v.w * v.w;
#pragma unroll
  for (int off = 32; off >= 1; off >>= 1) {
    s += __shfl_xor(s, off);
    s2 += __shfl_xor(s2, off);
  }
  __shared__ float ps[4], ps2[4];
  const int wave = tid >> 6, lane = tid & 63;
  if (lane == 0) { ps[wave] = s; ps2[wave] = s2; }
  __syncthreads();
  s = ps[0] + ps[1] + ps[2] + ps[3];
  s2 = ps2[0] + ps2[1] + ps2[2] + ps2[3];
  const float mu = s * (1.f / CC);
  const float rstd = rsqrtf(s2 * (1.f / CC) - mu * mu + 1e-5f);
  const float4 wv = reinterpret_cast<const float4*>(w)[tid];
  const float4 bv = reinterpret_cast<const float4*>(b)[tid];
  ushort4 o;
  o.x = f2bf((v.x - mu) * rstd * wv.x + bv.x);
  o.y = f2bf((v.y - mu) * rstd * wv.y + bv.y);
  o.z = f2bf((v.z - mu) * rstd * wv.z + bv.z);
  o.w = f2bf((v.w - mu) * rstd * wv.w + bv.w);
  reinterpret_cast<ushort4*>(y + (size_t)row * CC)[tid] = o;
}

// ------------------------------------------------------------------
// GEMM core (depth-3 pipeline): 128 x (NJ*32) tile.  Unchanged.
// ------------------------------------------------------------------
template<int NJ>
__device__ __forceinline__ void gemm_core(
    u16* smem, const u16* __restrict__ A, const u16* __restrict__ Bt,
    int K, int lda, int ldb, int bmi, int bni, f4 (&acc)[4][NJ]) {
  constexpr int BN = NJ * 32;
  constexpr int BBUF = BN * 32;
  u16* As = smem;
  u16* Bs = smem + 3 * 4096;
  const int tid = threadIdx.x;
  const int wave = tid >> 6, lane = tid & 63;
  const int wm = wave >> 1, wn = wave & 1;
  const int lg = lane >> 4, ll = lane & 15;

  const int trow = tid >> 2;
  const int tch  = (tid & 3) ^ ((trow >> 1) & 3);
  const u16* ga = A + (size_t)(bmi * 128 + trow) * lda + tch * 8;
  const u16* gb = Bt + (size_t)(bni * BN + trow) * ldb + tch * 8;
  const size_t g64a = (size_t)64 * lda;
  const size_t g64b = (size_t)64 * ldb;
  const int nt = K >> 5;

  auto GSTAGE = [&](int bi, int kt) {
    u16* la = &As[bi * 4096 + tid * 8];
    u16* lb = &Bs[bi * BBUF + tid * 8];
    const u16* gA = ga + kt * 32;
    const u16* gB = gb + kt * 32;
    __builtin_amdgcn_global_load_lds(AS1(gA), AS3(la), 16, 0, 0);
    __builtin_amdgcn_global_load_lds(AS1(gA + g64a), AS3(la + 2048), 16, 0, 0);
    __builtin_amdgcn_global_load_lds(AS1(gB), AS3(lb), 16, 0, 0);
    if constexpr (NJ == 4)
      __builtin_amdgcn_global_load_lds(AS1(gB + g64b), AS3(lb + 2048), 16, 0, 0);
  };

  GSTAGE(0, 0);
  GSTAGE(1, 1);
  GSTAGE(2, 2);
  int bi = 0;
  for (int t = 0; t < nt; t++) {
    const int ahead = nt - 1 - t;
    if constexpr (NJ == 4) {
      if (ahead >= 2)      asm volatile("s_waitcnt vmcnt(8)" ::: "memory");
      else if (ahead == 1) asm volatile("s_waitcnt vmcnt(4)" ::: "memory");
      else                 asm volatile("s_waitcnt vmcnt(0)" ::: "memory");
    } else {
      if (ahead >= 2)      asm volatile("s_waitcnt vmcnt(6)" ::: "memory");
      else if (ahead == 1) asm volatile("s_waitcnt vmcnt(3)" ::: "memory");
      else                 asm volatile("s_waitcnt vmcnt(0)" ::: "memory");
    }
    __builtin_amdgcn_s_barrier();
    __builtin_amdgcn_sched_barrier(0);

    const char* as_ = (const char*)(As + bi * 4096);
    const char* bs_ = (const char*)(Bs + bi * BBUF);
    bfrag af[4], bf[NJ];
#pragma unroll
    for (int i = 0; i < 4; i++)
      af[i] = *(const bfrag*)(as_ + swzAB((wm * 64 + i * 16 + ll) * 64 + lg * 16));
#pragma unroll
    for (int j = 0; j < NJ; j++)
      bf[j] = *(const bfrag*)(bs_ + swzAB((wn * (BN / 2) + j * 16 + ll) * 64 + lg * 16));

    __builtin_amdgcn_s_setprio(1);
#pragma unroll
    for (int i = 0; i < 4; i++)
#pragma unroll
      for (int j = 0; j < NJ; j++)
        acc[i][j] = __builtin_amdgcn_mfma_f32_16x16x32_bf16(af[i], bf[j], acc[i][j], 0, 0, 0);
    __builtin_amdgcn_s_setprio(0);

    __builtin_amdgcn_sched_barrier(0);
    __builtin_amdgcn_s_barrier();
    if (t + 3 < nt) GSTAGE(bi, t + 3);
    bi = (bi == 2) ? 0 : bi + 1;
  }
}

#define EPI_COORDS                                              \
  const int tid = threadIdx.x;                                  \
  const int wave = tid >> 6, lane = tid & 63;                   \
  const int wm = wave >> 1, wn = wave & 1;                      \
  const int lg = lane >> 4, ll = lane & 15;

// QKV: N=3072 (q|k|v), bias add, fold C^-0.5*log2e into q, LDS-staged scatter.
__global__ __launch_bounds__(256, 3) void gemm_qkv(
    const u16* __restrict__ A, const u16* __restrict__ Bt,
    const float* __restrict__ bq, const float* __restrict__ bk,
    const float* __restrict__ bv,
    u16* __restrict__ q, u16* __restrict__ k, u16* __restrict__ v) {
  __shared__ u16 smem[24576];
  XCD_SWZ_2D(bx, by)
  f4 acc[4][4] = {};
  gemm_core<4>(smem, A, Bt, CC, CC, CC, by, bx, acc);
  EPI_COORDS
  __syncthreads();
#pragma unroll
  for (int j = 0; j < 4; j++) {
    const int n = bx * 128 + wn * 64 + j * 16 + ll;
    const int sec = n >> 10, nn = n & 1023;
    const float bias = (sec == 0 ? bq : (sec == 1 ? bk : bv))[nn];
    const float scale = (sec == 0) ? 0.045084220027780106f : 1.0f;
#pragma unroll
    for (int i = 0; i < 4; i++)
#pragma unroll
      for (int r = 0; r < 4; r++)
        smem[(wm * 64 + i * 16 + lg * 4 + r) * 136 + wn * 64 + j * 16 + ll] =
            f2bf((acc[i][j][r] + bias) * scale);
  }
  __syncthreads();
  const int rr = tid >> 4, cb = (tid & 15) * 8;
#pragma unroll
  for (int R = 0; R < 8; R++) {
    const int row = R * 16 + rr;
    const int m = by * 128 + row, b = m >> 11, t = m & 2047;
    const int n = bx * 128 + cb;
    const int sec = n >> 10, nn = n & 1023, h = nn >> 6, d = nn & 63;
    u16* dst = sec == 0 ? q : (sec == 1 ? k : v);
    *(uint4*)&dst[(((size_t)b * HH + h) * TT + t) * HS + d] =
        *(const uint4*)&smem[row * 136 + cb];
  }
}

// FFN1: h = gelu_exact(A @ W1 + b1) -> bf16, LDS-staged writeback.
__global__ __launch_bounds__(256, 3) void gemm_ffn1(
    const u16* __restrict__ A, const u16* __restrict__ Bt,
    const float* __restrict__ b1, u16* __restrict__ hb) {
  __shared__ u16 smem[24576];
  XCD_SWZ_2D(bx, by)
  f4 acc[4][4] = {};
  gemm_core<4>(smem, A, Bt, CC, CC, CC, by, bx, acc);
  EPI_COORDS
  __syncthreads();
#pragma unroll
  for (int j = 0; j < 4; j++) {
    const int n = bx * 128 + wn * 64 + j * 16 + ll;
    const float bias = b1[n];
#pragma unroll
    for (int i = 0; i < 4; i++)
#pragma unroll
      for (int r = 0; r < 4; r++) {
        const float t = acc[i][j][r] + bias;
        const float g = 0.5f * t * (1.0f + erff(t * 0.70710678118654752f));
        smem[(wm * 64 + i * 16 + lg * 4 + r) * 136 + wn * 64 + j * 16 + ll] = f2bf(g);
      }
  }
  __syncthreads();
  const int rr = tid >> 4, cb = (tid & 15) * 8;
#pragma unroll
  for (int R = 0; R < 8; R++) {
    const int row = R * 16 + rr;
    *(uint4*)&hb[(size_t)(by * 128 + row) * FF + bx * 128 + cb] =
        *(const uint4*)&smem[row * 136 + cb];
  }
}

// FFN2 split-K chunk GEMM -> bf16 partials.
__global__ __launch_bounds__(256, 3) void gemm_ffn2sk(
    const u16* __restrict__ A, const u16* __restrict__ Bt,
    u16* __restrict__ p0, u16* __restrict__ p1) {
  __shared__ u16 smem[24576];
  int _fl = ((int)blockIdx.z * gridDim.y + blockIdx.y) * gridDim.x + blockIdx.x;
  const int _nw = gridDim.x * gridDim.y * gridDim.z;
  _fl = (_fl & 7) * (_nw >> 3) + (_fl >> 3);
  const int bx = _fl % gridDim.x;
  const int by = (_fl / gridDim.x) % gridDim.y;
  const int bz = _fl / (gridDim.x * gridDim.y);

  f4 acc[4][4] = {};
  gemm_core<4>(smem, A + bz * 2048, Bt + bz * 2048, 2048, FF, FF, by, bx, acc);
  EPI_COORDS
  __syncthreads();
#pragma unroll
  for (int j = 0; j < 4; j++)
#pragma unroll
    for (int i = 0; i < 4; i++)
#pragma unroll
      for (int r = 0; r < 4; r++)
        smem[(wm * 64 + i * 16 + lg * 4 + r) * 136 + wn * 64 + j * 16 + ll] =
            f2bf(acc[i][j][r]);
  __syncthreads();
  u16* pp = bz ? p1 : p0;
  const int rr = tid >> 4, cb = (tid & 15) * 8;
#pragma unroll
  for (int R = 0; R < 8; R++) {
    const int row = R * 16 + rr;
    *(uint4*)&pp[(size_t)(by * 128 + row) * CC + bx * 128 + cb] =
        *(const uint4*)&smem[row * 136 + cb];
  }
}

// FFN2 reduce: dout = dout(residual) + b2 + p0 + p1.
__global__ __launch_bounds__(256) void ffn2_reduce(
    const u16* __restrict__ p0, const u16* __restrict__ p1,
    const float* __restrict__ b2, float* __restrict__ dout) {
  const int gid = blockIdx.x * 256 + threadIdx.x;
  const int n0 = (gid * 8) & (CC - 1);
  const uint4 a = ((const uint4*)p0)[gid];
  const uint4 c = ((const uint4*)p1)[gid];
  const u16* au = (const u16*)&a;
  const u16* cu = (const u16*)&c;
  float4 d0 = ((const float4*)dout)[gid * 2];
  float4 d1 = ((const float4*)dout)[gid * 2 + 1];
  const float4 w0 = *(const float4*)&b2[n0];
  const float4 w1 = *(const float4*)&b2[n0 + 4];
  d0.x += w0.x + bf2f(au[0]) + bf2f(cu[0]);
  d0.y += w0.y + bf2f(au[1]) + bf2f(cu[1]);
  d0.z += w0.z + bf2f(au[2]) + bf2f(cu[2]);
  d0.w += w0.w + bf2f(au[3]) + bf2f(cu[3]);
  d1.x += w1.x + bf2f(au[4]) + bf2f(cu[4]);
  d1.y += w1.y + bf2f(au[5]) + bf2f(cu[5]);
  d1.z += w1.z + bf2f(au[6]) + bf2f(cu[6]);
  d1.w += w1.w + bf2f(au[7]) + bf2f(cu[7]);
  ((float4*)dout)[gid * 2] = d0;
  ((float4*)dout)[gid * 2 + 1] = d1;
}

// PROJ: out = x + (A @ Wp + bp) -> f32 (= d_out).  BN=64, NJ=2.
__global__ __launch_bounds__(256, 3) void gemm_proj(
    const u16* __restrict__ A, const u16* __restrict__ Bt,
    const float* __restrict__ bp, const float* __restrict__ x,
    float* __restrict__ outw) {
  __shared__ u16 smem[18432];
  XCD_SWZ_2D(bx, by)
  f4 acc[4][2] = {};
  gemm_core<2>(smem, A, Bt, CC, CC, CC, by, bx, acc);
  EPI_COORDS
#pragma unroll
  for (int i = 0; i < 4; i++)
#pragma unroll
    for (int j = 0; j < 2; j++) {
      const int n = bx * 64 + wn * 32 + j * 16 + ll;
      const float bias = bp[n];
#pragma unroll
      for (int r = 0; r < 4; r++) {
        const int m = by * 128 + wm * 64 + i * 16 + lg * 4 + r;
        const size_t idx = (size_t)m * CC + n;
        outw[idx] = acc[i][j][r] + bias + x[idx];
      }
    }
}

// ------------------------------------------------------------------
// Flash attention fwd v4: QBLK=64 (16 q-rows/wave), grid (32,32)=1024
// blocks, 40KB LDS -> 4 blocks/CU (16 waves/CU) for latency hiding.
// Same swapped-operand QK^T + lane-local softmax + wave-private P +
// double-buffered K/V with counted vmcnt.  exp2 domain (Q pre-scaled).
// ------------------------------------------------------------------
__global__ __launch_bounds__(256, 4) void attn_kernel(
    const u16* __restrict__ Q, const u16* __restrict__ Kb,
    const u16* __restrict__ Vt, u16* __restrict__ Ao) {
  __shared__ __align__(1024) u16 Ks[2][64 * 64];  // [s:64][d:64], swizzled
  __shared__ __align__(1024) u16 Vs[2][64 * 64];  // [d:64][s:64], swizzled
  __shared__ __align__(1024) u16 Ps[4][16 * 64];  // per-wave [q:16][s:64], swizzled
  const int bh = blockIdx.y, qt = blockIdx.x;
  const int tid = threadIdx.x, wave = tid >> 6, lane = tid & 63;
  const int lg = lane >> 4, ll = lane & 15;

  // Q fragments as MFMA B-operand: lane ll holds Q row ll, d contiguous
  bfrag qf[2];
  const u16* Qb = Q + ((size_t)bh * TT + qt * 64 + wave * 16) * HS;
#pragma unroll
  for (int dc = 0; dc < 2; dc++)
    qf[dc] = *(const bfrag*)&Qb[ll * HS + dc * 32 + lg * 8];

  f4 o[4] = {};
  float mrun = -INFINITY, lrun = 0.f;

  const int trow = tid >> 3;
  const int tch  = (tid & 7) ^ (trow & 7);
  const u16* gk = Kb + ((size_t)bh * TT + trow) * HS + tch * 8;
  const u16* gv = Vt + ((size_t)bh * HS + trow) * TT + tch * 8;

  char* const pw = (char*)Ps[wave];

#define STAGE(bufi, stt)                                                          \
  do {                                                                            \
    u16* lk = &Ks[bufi][tid * 8];                                                 \
    u16* lv = &Vs[bufi][tid * 8];                                                 \
    __builtin_amdgcn_global_load_lds(AS1(gk + (size_t)(stt) * HS), AS3(lk), 16, 0, 0); \
    __builtin_amdgcn_global_load_lds(AS1(gk + (size_t)(stt) * HS + 32 * HS), AS3(lk + 2048), 16, 0, 0); \
    __builtin_amdgcn_global_load_lds(AS1(gv + (stt)), AS3(lv), 16, 0, 0);         \
    __builtin_amdgcn_global_load_lds(AS1(gv + (stt) + (size_t)32 * TT), AS3(lv + 2048), 16, 0, 0); \
  } while (0)

  STAGE(0, 0);
  int cur = 0;

  for (int st = 0; st < TT; st += 64) {
    if (st + 64 < TT) {
      STAGE(cur ^ 1, st + 64);
      asm volatile("s_waitcnt vmcnt(4)" ::: "memory");
    } else {
      asm volatile("s_waitcnt vmcnt(0)" ::: "memory");
    }
    __builtin_amdgcn_s_barrier();
    __builtin_amdgcn_sched_barrier(0);

    const char* kbuf = (const char*)Ks[cur];
    const char* vbuf = (const char*)Vs[cur];

    // S^T = K Q^T : lane (lg,ll) holds S[q = ll][k = kb*16 + lg*4 + r]
    f4 p[4];
#pragma unroll
    for (int kb = 0; kb < 4; kb++) {
      const int row = kb * 16 + ll;
      const bfrag k0 = *(const bfrag*)(kbuf + swz128(row * 128 + lg * 16));
      const bfrag k1 = *(const bfrag*)(kbuf + swz128(row * 128 + 64 + lg * 16));
      f4 z = {0.f, 0.f, 0.f, 0.f};
      z = __builtin_amdgcn_mfma_f32_16x16x32_bf16(k0, qf[0], z, 0, 0, 0);
      p[kb] = __builtin_amdgcn_mfma_f32_16x16x32_bf16(k1, qf[1], z, 0, 0, 0);
    }

    // online softmax: lane-local over 16 values + 2 cross-group shuffles
    {
      float pm = p[0][0];
#pragma unroll
      for (int kb = 0; kb < 4; kb++)
#pragma unroll
        for (int r = 0; r < 4; r++)
          if (kb | r) pm = fmaxf(pm, p[kb][r]);
      pm = fmaxf(pm, __shfl_xor(pm, 16));
      pm = fmaxf(pm, __shfl_xor(pm, 32));
      const float mn = fmaxf(mrun, pm);
      const float al = exp2f(mrun - mn);
      mrun = mn;
      float rs = 0.f;
#pragma unroll
      for (int kb = 0; kb < 4; kb++)
#pragma unroll
        for (int r = 0; r < 4; r++) {
          const float e = exp2f(p[kb][r] - mn);
          p[kb][r] = e;
          rs += e;
        }
      rs += __shfl_xor(rs, 16);
      rs += __shfl_xor(rs, 32);
      lrun = lrun * al + rs;
#pragma unroll
      for (int fo = 0; fo < 4; fo++) o[fo] *= al;
#pragma unroll
      for (int kb = 0; kb < 4; kb++) {
        union { uint2 v; __bf16 h[4]; } w;
        w.h[0] = (__bf16)p[kb][0];
        w.h[1] = (__bf16)p[kb][1];
        w.h[2] = (__bf16)p[kb][2];
        w.h[3] = (__bf16)p[kb][3];
        *(uint2*)(pw + swz128(ll * 128 + kb * 32 + lg * 8)) = w.v;
      }
    }

    // O^T += V^T P : A = V^T rows (d), B = P rows (q).  Wave-private P.
#pragma unroll
    for (int ks = 0; ks < 2; ks++) {
      const bfrag pb = *(const bfrag*)(pw + swz128(ll * 128 + ks * 64 + lg * 16));
#pragma unroll
      for (int fo = 0; fo < 4; fo++) {
        const bfrag vf = *(const bfrag*)(vbuf + swz128((fo * 16 + ll) * 128 + ks * 64 + lg * 16));
        o[fo] = __builtin_amdgcn_mfma_f32_16x16x32_bf16(vf, pb, o[fo], 0, 0, 0);
      }
    }

    __builtin_amdgcn_sched_barrier(0);
    __builtin_amdgcn_s_barrier();
    cur ^= 1;
  }
#undef STAGE

  // epilogue: O^T / l -> [B*T][C] bf16.  lane writes q = ll, d = fo*16+lg*4+0..3
  const int b = bh >> 4, h = bh & 15;
  const float inv = 1.0f / lrun;
  const int t = qt * 64 + wave * 16 + ll;
#pragma unroll
  for (int fo = 0; fo < 4; fo++) {
    union { uint2 v; __bf16 hh[4]; } w;
    w.hh[0] = (__bf16)(o[fo][0] * inv);
    w.hh[1] = (__bf16)(o[fo][1] * inv);
    w.hh[2] = (__bf16)(o[fo][2] * inv);
    w.hh[3] = (__bf16)(o[fo][3] * inv);
    *(uint2*)&Ao[((size_t)b * TT + t) * CC + h * HS + fo * 16 + lg * 4] = w.v;
  }
}

// ------------------------------------------------------------------
extern "C" void kernel_launch(void* const* d_in, const int* in_sizes, int n_in,
                              void* d_out, int out_size, void* d_ws, size_t ws_size,
                              hipStream_t stream) {
  const float* x    = (const float*)d_in[0];
  const float* Wq   = (const float*)d_in[1];
  const float* bq   = (const float*)d_in[2];
  const float* Wk   = (const float*)d_in[3];
  const float* bk   = (const float*)d_in[4];
  const float* Wv   = (const float*)d_in[5];
  const float* bv   = (const float*)d_in[6];
  const float* Wp   = (const float*)d_in[7];
  const float* bp   = (const float*)d_in[8];
  const float* W1   = (const float*)d_in[9];
  const float* b1   = (const float*)d_in[10];
  const float* W2   = (const float*)d_in[11];
  const float* b2   = (const float*)d_in[12];
  const float* ln1w = (const float*)d_in[13];
  const float* ln1b = (const float*)d_in[14];
  const float* ln2w = (const float*)d_in[15];
  const float* ln2b = (const float*)d_in[16];
  float* dout = (float*)d_out;

  char* ws = (char*)d_ws;
  u16* wqkv = (u16*)(ws + 0);          // [3072][1024]  (dead after qkv)
  u16* wpt  = (u16*)(ws + 6291456);    // [1024][1024]  (dead after proj)
  u16* w1t  = (u16*)(ws + 8388608);    // [4096][1024]  (dead after ffn1)
  u16* w2t  = (u16*)(ws + 16777216);   // [1024][4096]
  u16* xn   = (u16*)(ws + 25165824);   // [4096][1024]  (reused for LN2)
  u16* qb   = (u16*)(ws + 33554432);   // [32][2048][64]
  u16* kb   = (u16*)(ws + 41943040);
  u16* vb   = (u16*)(ws + 50331648);
  u16* vt   = (u16*)(ws + 58720256);   // [32][64][2048]
  u16* ao   = (u16*)(ws + 67108864);   // [4096][1024]
  u16* hb   = qb;                      // FFN hidden overlays q/k/v/vt
  u16* pk0  = (u16*)(ws + 0);          // ffn2 partial over wqkv+wpt
  u16* pk1  = (u16*)(ws + 8388608);    // ffn2 partial over w1t

  dim3 blk256(256);
  dim3 blkT(32, 8);

  // weight prep: transpose to [N][K] bf16
  tr_f32_bf16<<<dim3(2, 32, 16), blkT, 0, stream>>>(Wq, wqkv,               1024,   64, 65536LL, 65536LL, 1024);
  tr_f32_bf16<<<dim3(2, 32, 16), blkT, 0, stream>>>(Wk, wqkv + 1024 * 1024, 1024,   64, 65536LL, 65536LL, 1024);
  tr_f32_bf16<<<dim3(2, 32, 16), blkT, 0, stream>>>(Wv, wqkv + 2048 * 1024, 1024,   64, 65536LL, 65536LL, 1024);
  tr_f32_bf16<<<dim3(32, 32, 1),  blkT, 0, stream>>>(Wp, wpt, 1024, 1024, 0LL, 0LL, 1024);
  tr_f32_bf16<<<dim3(128, 32, 1), blkT, 0, stream>>>(W1, w1t, 1024, 4096, 0LL, 0LL, 1024);
  tr_f32_bf16<<<dim3(32, 128, 1), blkT, 0, stream>>>(W2, w2t, 4096, 1024, 0LL, 0LL, 4096);

  // LN1 -> xn (bf16)
  ln_kernel<<<dim3(MT), blk256, 0, stream>>>(x, ln1w, ln1b, xn);

  // QKV projection (q pre-scaled by C^-0.5 * log2e)
  gemm_qkv<<<dim3(24, 32), blk256, 0, stream>>>(xn, wqkv, bq, bk, bv, qb, kb, vb);

  // V -> Vt [bh][64][2048]
  tr_bf16<<<dim3(2, 64, 32), blkT, 0, stream>>>(vb, vt, 2048, 64, 131072LL, 131072LL, 2048);

  // attention (QBLK=64 -> 1024 blocks, 4 blocks/CU)
  attn_kernel<<<dim3(32, 32), blk256, 0, stream>>>(qb, kb, vt, ao);

  // out = x + ao @ Wp + bp   (f32, into d_out)
  gemm_proj<<<dim3(16, 32), blk256, 0, stream>>>(ao, wpt, bp, x, dout);

  // LN2 -> xn (reuse)
  ln_kernel<<<dim3(MT), blk256, 0, stream>>>(dout, ln2w, ln2b, xn);

  // FFN
  gemm_ffn1<<<dim3(32, 32), blk256, 0, stream>>>(xn, w1t, b1, hb);
  gemm_ffn2sk<<<dim3(8, 32, 2), blk256, 0, stream>>>(hb, w2t, pk0, pk1);
  ffn2_reduce<<<dim3(MT * CC / 8 / 256), blk256, 0, stream>>>(pk0, pk1, b2, dout);
}

// Round 9
// 277.206 us; speedup vs baseline: 1.0833x; 1.0010x over previous
//
#include <hip/hip_runtime.h>
#include <math.h>

// ---- problem dims (B=2, T=2048, C=1024, H=16, HS=64) ----
#define BB 2
#define TT 2048
#define CC 1024
#define HH 16
#define HS 64
#define MT 4096   // B*T
#define FF 4096   // 4*C

typedef unsigned short u16;
typedef __bf16 bfrag __attribute__((ext_vector_type(8)));
typedef float f4 __attribute__((ext_vector_type(4)));

#define AS1(p) ((const __attribute__((address_space(1))) void*)(p))
#define AS3(p) ((__attribute__((address_space(3))) void*)(p))

__device__ __forceinline__ u16 f2bf(float f) {
  union { float f; unsigned u; } a; a.f = f;
  return (u16)((a.u + 0x7fffu + ((a.u >> 16) & 1u)) >> 16);
}
__device__ __forceinline__ float bf2f(u16 u) {
  union { unsigned u; float f; } a; a.u = ((unsigned)u) << 16; return a.f;
}

// XOR-swizzle for 128-byte-row LDS tiles (attention)
__device__ __forceinline__ int swz128(int byteoff) {
  return byteoff ^ (((byteoff >> 7) & 7) << 4);
}
// XOR-swizzle for 64-byte-row LDS tiles (GEMM A/B)
__device__ __forceinline__ int swzAB(int byteoff) {
  return byteoff ^ (((byteoff >> 7) & 3) << 4);
}

// XCD-aware chunked swizzle (T1).  Requires nwg % 8 == 0.
#define XCD_SWZ_2D(BX, BY)                                                     \
  int _fl = (int)blockIdx.y * gridDim.x + blockIdx.x;                          \
  const int _nw = gridDim.x * gridDim.y;                                       \
  _fl = (_fl & 7) * (_nw >> 3) + (_fl >> 3);                                   \
  const int BX = _fl % gridDim.x;                                              \
  const int BY = _fl / gridDim.x;

// ------------------------------------------------------------------
// Tiled transpose f32 -> bf16.
// ------------------------------------------------------------------
__global__ void tr_f32_bf16(const float* __restrict__ src, u16* __restrict__ dst,
                            int R, int Cc, long long sb, long long db, int dld) {
  __shared__ float t[32][33];
  const int bz = blockIdx.z;
  const int r0 = blockIdx.y * 32, c0 = blockIdx.x * 32;
  const int tx = threadIdx.x, ty = threadIdx.y;
  const float* s = src + bz * sb;
  u16* d = dst + bz * db;
#pragma unroll
  for (int i = 0; i < 4; i++)
    t[ty + i * 8][tx] = s[(size_t)(r0 + ty + i * 8) * Cc + c0 + tx];
  __syncthreads();
#pragma unroll
  for (int i = 0; i < 4; i++)
    d[(size_t)(c0 + ty + i * 8) * dld + r0 + tx] = f2bf(t[tx][ty + i * 8]);
}

// bf16 -> bf16 transpose (for V)
__global__ void tr_bf16(const u16* __restrict__ src, u16* __restrict__ dst,
                        int R, int Cc, long long sb, long long db, int dld) {
  __shared__ u16 t[32][33];
  const int bz = blockIdx.z;
  const int r0 = blockIdx.y * 32, c0 = blockIdx.x * 32;
  const int tx = threadIdx.x, ty = threadIdx.y;
  const u16* s = src + bz * sb;
  u16* d = dst + bz * db;
#pragma unroll
  for (int i = 0; i < 4; i++)
    t[ty + i * 8][tx] = s[(size_t)(r0 + ty + i * 8) * Cc + c0 + tx];
  __syncthreads();
#pragma unroll
  for (int i = 0; i < 4; i++)
    d[(size_t)(c0 + ty + i * 8) * dld + r0 + tx] = t[tx][ty + i * 8];
}

// ------------------------------------------------------------------
// LayerNorm: one block (256 thr) per row of [4096][1024] f32 -> bf16
// ------------------------------------------------------------------
__global__ __launch_bounds__(256) void ln_kernel(
    const float* __restrict__ x, const float* __restrict__ w,
    const float* __restrict__ b, u16* __restrict__ y) {
  const int row = blockIdx.x, tid = threadIdx.x;
  const float4 v = reinterpret_cast<const float4*>(x + (size_t)row * CC)[tid];
  float s = v.x + v.y + v.z + v.w;
  float s2 = v.x * v.x + v.y * v.y + v.z * v.z + v.w * v.w;
#pragma unroll
  for (int off = 32; off >= 1; off >>= 1) {
    s += __shfl_xor(s, off);
    s2 += __shfl_xor(s2, off);
  }
  __shared__ float ps[4], ps2[4];
  const int wave = tid >> 6, lane = tid & 63;
  if (lane == 0) { ps[wave] = s; ps2[wave] = s2; }
  __syncthreads();
  s = ps[0] + ps[1] + ps[2] + ps[3];
  s2 = ps2[0] + ps2[1] + ps2[2] + ps2[3];
  const float mu = s * (1.f / CC);
  const float rstd = rsqrtf(s2 * (1.f / CC) - mu * mu + 1e-5f);
  const float4 wv = reinterpret_cast<const float4*>(w)[tid];
  const float4 bv = reinterpret_cast<const float4*>(b)[tid];
  ushort4 o;
  o.x = f2bf((v.x - mu) * rstd * wv.x + bv.x);
  o.y = f2bf((v.y - mu) * rstd * wv.y + bv.y);
  o.z = f2bf((v.z - mu) * rstd * wv.z + bv.z);
  o.w = f2bf((v.w - mu) * rstd * wv.w + bv.w);
  reinterpret_cast<ushort4*>(y + (size_t)row * CC)[tid] = o;
}

// ------------------------------------------------------------------
// GEMM core (depth-3 pipeline): 128 x (NJ*32) tile.  Unchanged.
// ------------------------------------------------------------------
template<int NJ>
__device__ __forceinline__ void gemm_core(
    u16* smem, const u16* __restrict__ A, const u16* __restrict__ Bt,
    int K, int lda, int ldb, int bmi, int bni, f4 (&acc)[4][NJ]) {
  constexpr int BN = NJ * 32;
  constexpr int BBUF = BN * 32;
  u16* As = smem;
  u16* Bs = smem + 3 * 4096;
  const int tid = threadIdx.x;
  const int wave = tid >> 6, lane = tid & 63;
  const int wm = wave >> 1, wn = wave & 1;
  const int lg = lane >> 4, ll = lane & 15;

  const int trow = tid >> 2;
  const int tch  = (tid & 3) ^ ((trow >> 1) & 3);
  const u16* ga = A + (size_t)(bmi * 128 + trow) * lda + tch * 8;
  const u16* gb = Bt + (size_t)(bni * BN + trow) * ldb + tch * 8;
  const size_t g64a = (size_t)64 * lda;
  const size_t g64b = (size_t)64 * ldb;
  const int nt = K >> 5;

  auto GSTAGE = [&](int bi, int kt) {
    u16* la = &As[bi * 4096 + tid * 8];
    u16* lb = &Bs[bi * BBUF + tid * 8];
    const u16* gA = ga + kt * 32;
    const u16* gB = gb + kt * 32;
    __builtin_amdgcn_global_load_lds(AS1(gA), AS3(la), 16, 0, 0);
    __builtin_amdgcn_global_load_lds(AS1(gA + g64a), AS3(la + 2048), 16, 0, 0);
    __builtin_amdgcn_global_load_lds(AS1(gB), AS3(lb), 16, 0, 0);
    if constexpr (NJ == 4)
      __builtin_amdgcn_global_load_lds(AS1(gB + g64b), AS3(lb + 2048), 16, 0, 0);
  };

  GSTAGE(0, 0);
  GSTAGE(1, 1);
  GSTAGE(2, 2);
  int bi = 0;
  for (int t = 0; t < nt; t++) {
    const int ahead = nt - 1 - t;
    if constexpr (NJ == 4) {
      if (ahead >= 2)      asm volatile("s_waitcnt vmcnt(8)" ::: "memory");
      else if (ahead == 1) asm volatile("s_waitcnt vmcnt(4)" ::: "memory");
      else                 asm volatile("s_waitcnt vmcnt(0)" ::: "memory");
    } else {
      if (ahead >= 2)      asm volatile("s_waitcnt vmcnt(6)" ::: "memory");
      else if (ahead == 1) asm volatile("s_waitcnt vmcnt(3)" ::: "memory");
      else                 asm volatile("s_waitcnt vmcnt(0)" ::: "memory");
    }
    __builtin_amdgcn_s_barrier();
    __builtin_amdgcn_sched_barrier(0);

    const char* as_ = (const char*)(As + bi * 4096);
    const char* bs_ = (const char*)(Bs + bi * BBUF);
    bfrag af[4], bf[NJ];
#pragma unroll
    for (int i = 0; i < 4; i++)
      af[i] = *(const bfrag*)(as_ + swzAB((wm * 64 + i * 16 + ll) * 64 + lg * 16));
#pragma unroll
    for (int j = 0; j < NJ; j++)
      bf[j] = *(const bfrag*)(bs_ + swzAB((wn * (BN / 2) + j * 16 + ll) * 64 + lg * 16));

    __builtin_amdgcn_s_setprio(1);
#pragma unroll
    for (int i = 0; i < 4; i++)
#pragma unroll
      for (int j = 0; j < NJ; j++)
        acc[i][j] = __builtin_amdgcn_mfma_f32_16x16x32_bf16(af[i], bf[j], acc[i][j], 0, 0, 0);
    __builtin_amdgcn_s_setprio(0);

    __builtin_amdgcn_sched_barrier(0);
    __builtin_amdgcn_s_barrier();
    if (t + 3 < nt) GSTAGE(bi, t + 3);
    bi = (bi == 2) ? 0 : bi + 1;
  }
}

#define EPI_COORDS                                              \
  const int tid = threadIdx.x;                                  \
  const int wave = tid >> 6, lane = tid & 63;                   \
  const int wm = wave >> 1, wn = wave & 1;                      \
  const int lg = lane >> 4, ll = lane & 15;

// QKV: N=3072 (q|k|v), bias add, fold C^-0.5*log2e into q, LDS-staged scatter.
__global__ __launch_bounds__(256, 3) void gemm_qkv(
    const u16* __restrict__ A, const u16* __restrict__ Bt,
    const float* __restrict__ bq, const float* __restrict__ bk,
    const float* __restrict__ bv,
    u16* __restrict__ q, u16* __restrict__ k, u16* __restrict__ v) {
  __shared__ u16 smem[24576];
  XCD_SWZ_2D(bx, by)
  f4 acc[4][4] = {};
  gemm_core<4>(smem, A, Bt, CC, CC, CC, by, bx, acc);
  EPI_COORDS
  __syncthreads();
#pragma unroll
  for (int j = 0; j < 4; j++) {
    const int n = bx * 128 + wn * 64 + j * 16 + ll;
    const int sec = n >> 10, nn = n & 1023;
    const float bias = (sec == 0 ? bq : (sec == 1 ? bk : bv))[nn];
    const float scale = (sec == 0) ? 0.045084220027780106f : 1.0f;
#pragma unroll
    for (int i = 0; i < 4; i++)
#pragma unroll
      for (int r = 0; r < 4; r++)
        smem[(wm * 64 + i * 16 + lg * 4 + r) * 136 + wn * 64 + j * 16 + ll] =
            f2bf((acc[i][j][r] + bias) * scale);
  }
  __syncthreads();
  const int rr = tid >> 4, cb = (tid & 15) * 8;
#pragma unroll
  for (int R = 0; R < 8; R++) {
    const int row = R * 16 + rr;
    const int m = by * 128 + row, b = m >> 11, t = m & 2047;
    const int n = bx * 128 + cb;
    const int sec = n >> 10, nn = n & 1023, h = nn >> 6, d = nn & 63;
    u16* dst = sec == 0 ? q : (sec == 1 ? k : v);
    *(uint4*)&dst[(((size_t)b * HH + h) * TT + t) * HS + d] =
        *(const uint4*)&smem[row * 136 + cb];
  }
}

// FFN1: h = gelu_exact(A @ W1 + b1) -> bf16, LDS-staged writeback.
__global__ __launch_bounds__(256, 3) void gemm_ffn1(
    const u16* __restrict__ A, const u16* __restrict__ Bt,
    const float* __restrict__ b1, u16* __restrict__ hb) {
  __shared__ u16 smem[24576];
  XCD_SWZ_2D(bx, by)
  f4 acc[4][4] = {};
  gemm_core<4>(smem, A, Bt, CC, CC, CC, by, bx, acc);
  EPI_COORDS
  __syncthreads();
#pragma unroll
  for (int j = 0; j < 4; j++) {
    const int n = bx * 128 + wn * 64 + j * 16 + ll;
    const float bias = b1[n];
#pragma unroll
    for (int i = 0; i < 4; i++)
#pragma unroll
      for (int r = 0; r < 4; r++) {
        const float t = acc[i][j][r] + bias;
        const float g = 0.5f * t * (1.0f + erff(t * 0.70710678118654752f));
        smem[(wm * 64 + i * 16 + lg * 4 + r) * 136 + wn * 64 + j * 16 + ll] = f2bf(g);
      }
  }
  __syncthreads();
  const int rr = tid >> 4, cb = (tid & 15) * 8;
#pragma unroll
  for (int R = 0; R < 8; R++) {
    const int row = R * 16 + rr;
    *(uint4*)&hb[(size_t)(by * 128 + row) * FF + bx * 128 + cb] =
        *(const uint4*)&smem[row * 136 + cb];
  }
}

// FFN2 split-K chunk GEMM -> bf16 partials.
__global__ __launch_bounds__(256, 3) void gemm_ffn2sk(
    const u16* __restrict__ A, const u16* __restrict__ Bt,
    u16* __restrict__ p0, u16* __restrict__ p1) {
  __shared__ u16 smem[24576];
  int _fl = ((int)blockIdx.z * gridDim.y + blockIdx.y) * gridDim.x + blockIdx.x;
  const int _nw = gridDim.x * gridDim.y * gridDim.z;
  _fl = (_fl & 7) * (_nw >> 3) + (_fl >> 3);
  const int bx = _fl % gridDim.x;
  const int by = (_fl / gridDim.x) % gridDim.y;
  const int bz = _fl / (gridDim.x * gridDim.y);

  f4 acc[4][4] = {};
  gemm_core<4>(smem, A + bz * 2048, Bt + bz * 2048, 2048, FF, FF, by, bx, acc);
  EPI_COORDS
  __syncthreads();
#pragma unroll
  for (int j = 0; j < 4; j++)
#pragma unroll
    for (int i = 0; i < 4; i++)
#pragma unroll
      for (int r = 0; r < 4; r++)
        smem[(wm * 64 + i * 16 + lg * 4 + r) * 136 + wn * 64 + j * 16 + ll] =
            f2bf(acc[i][j][r]);
  __syncthreads();
  u16* pp = bz ? p1 : p0;
  const int rr = tid >> 4, cb = (tid & 15) * 8;
#pragma unroll
  for (int R = 0; R < 8; R++) {
    const int row = R * 16 + rr;
    *(uint4*)&pp[(size_t)(by * 128 + row) * CC + bx * 128 + cb] =
        *(const uint4*)&smem[row * 136 + cb];
  }
}

// FFN2 reduce: dout = dout(residual) + b2 + p0 + p1.
__global__ __launch_bounds__(256) void ffn2_reduce(
    const u16* __restrict__ p0, const u16* __restrict__ p1,
    const float* __restrict__ b2, float* __restrict__ dout) {
  const int gid = blockIdx.x * 256 + threadIdx.x;
  const int n0 = (gid * 8) & (CC - 1);
  const uint4 a = ((const uint4*)p0)[gid];
  const uint4 c = ((const uint4*)p1)[gid];
  const u16* au = (const u16*)&a;
  const u16* cu = (const u16*)&c;
  float4 d0 = ((const float4*)dout)[gid * 2];
  float4 d1 = ((const float4*)dout)[gid * 2 + 1];
  const float4 w0 = *(const float4*)&b2[n0];
  const float4 w1 = *(const float4*)&b2[n0 + 4];
  d0.x += w0.x + bf2f(au[0]) + bf2f(cu[0]);
  d0.y += w0.y + bf2f(au[1]) + bf2f(cu[1]);
  d0.z += w0.z + bf2f(au[2]) + bf2f(cu[2]);
  d0.w += w0.w + bf2f(au[3]) + bf2f(cu[3]);
  d1.x += w1.x + bf2f(au[4]) + bf2f(cu[4]);
  d1.y += w1.y + bf2f(au[5]) + bf2f(cu[5]);
  d1.z += w1.z + bf2f(au[6]) + bf2f(cu[6]);
  d1.w += w1.w + bf2f(au[7]) + bf2f(cu[7]);
  ((float4*)dout)[gid * 2] = d0;
  ((float4*)dout)[gid * 2 + 1] = d1;
}

// PROJ: out = x + (A @ Wp + bp) -> f32 (= d_out).  BN=64, NJ=2.
__global__ __launch_bounds__(256, 3) void gemm_proj(
    const u16* __restrict__ A, const u16* __restrict__ Bt,
    const float* __restrict__ bp, const float* __restrict__ x,
    float* __restrict__ outw) {
  __shared__ u16 smem[18432];
  XCD_SWZ_2D(bx, by)
  f4 acc[4][2] = {};
  gemm_core<2>(smem, A, Bt, CC, CC, CC, by, bx, acc);
  EPI_COORDS
#pragma unroll
  for (int i = 0; i < 4; i++)
#pragma unroll
    for (int j = 0; j < 2; j++) {
      const int n = bx * 64 + wn * 32 + j * 16 + ll;
      const float bias = bp[n];
#pragma unroll
      for (int r = 0; r < 4; r++) {
        const int m = by * 128 + wm * 64 + i * 16 + lg * 4 + r;
        const size_t idx = (size_t)m * CC + n;
        outw[idx] = acc[i][j][r] + bias + x[idx];
      }
    }
}

// ------------------------------------------------------------------
// Flash attention fwd v5: QBLK=64, 4 blocks/CU.  New this round:
// (1) XCD-affinity block remap: each XCD owns 4 bh x all 32 qt, so each
//     bh's K/V (512KB) stays resident in ONE XCD's L2 (4x512KB = 2MB < 4MB).
// (2) log-depth tree max/sum (depth 4 vs 15-16 serial) + defer-max (T13).
// (3) all swizzled LDS byte-offsets hoisted out of the kv-loop.
// ------------------------------------------------------------------
__global__ __launch_bounds__(256, 4) void attn_kernel(
    const u16* __restrict__ Q, const u16* __restrict__ Kb,
    const u16* __restrict__ Vt, u16* __restrict__ Ao) {
  __shared__ __align__(1024) u16 Ks[2][64 * 64];  // [s:64][d:64], swizzled
  __shared__ __align__(1024) u16 Vs[2][64 * 64];  // [d:64][s:64], swizzled
  __shared__ __align__(1024) u16 Ps[4][16 * 64];  // per-wave [q:16][s:64], swizzled

  // XCD-affinity remap: hw block fl -> xcd = fl&7; xcd owns bh in
  // {xcd, xcd+8, xcd+16, xcd+24} and walks qt 0..31 contiguously.
  const int fl = (int)blockIdx.y * 32 + blockIdx.x;
  const int idx = fl >> 3;
  const int bh = (idx >> 5) * 8 + (fl & 7);
  const int qt = idx & 31;

  const int tid = threadIdx.x, wave = tid >> 6, lane = tid & 63;
  const int lg = lane >> 4, ll = lane & 15;

  // Q fragments as MFMA B-operand: lane ll holds Q row ll, d contiguous
  bfrag qf[2];
  const u16* Qb = Q + ((size_t)bh * TT + qt * 64 + wave * 16) * HS;
#pragma unroll
  for (int dc = 0; dc < 2; dc++)
    qf[dc] = *(const bfrag*)&Qb[ll * HS + dc * 32 + lg * 8];

  f4 o[4] = {};
  float mrun = -INFINITY, lrun = 0.f;

  const int trow = tid >> 3;
  const int tch  = (tid & 7) ^ (trow & 7);
  const u16* gk = Kb + ((size_t)bh * TT + trow) * HS + tch * 8;
  const u16* gv = Vt + ((size_t)bh * HS + trow) * TT + tch * 8;

  char* const pw = (char*)Ps[wave];

  // hoisted swizzled byte offsets (loop-invariant; all indexing unrolled)
  int koff0[4], koff1[4], pwoff[4], proff[2], voff[2][4];
#pragma unroll
  for (int kb = 0; kb < 4; kb++) {
    const int row = kb * 16 + ll;
    koff0[kb] = swz128(row * 128 + lg * 16);
    koff1[kb] = swz128(row * 128 + 64 + lg * 16);
    pwoff[kb] = swz128(ll * 128 + kb * 32 + lg * 8);
  }
#pragma unroll
  for (int ks = 0; ks < 2; ks++) {
    proff[ks] = swz128(ll * 128 + ks * 64 + lg * 16);
#pragma unroll
    for (int fo = 0; fo < 4; fo++)
      voff[ks][fo] = swz128((fo * 16 + ll) * 128 + ks * 64 + lg * 16);
  }

#define STAGE(bufi, stt)                                                          \
  do {                                                                            \
    u16* lk = &Ks[bufi][tid * 8];                                                 \
    u16* lv = &Vs[bufi][tid * 8];                                                 \
    __builtin_amdgcn_global_load_lds(AS1(gk + (size_t)(stt) * HS), AS3(lk), 16, 0, 0); \
    __builtin_amdgcn_global_load_lds(AS1(gk + (size_t)(stt) * HS + 32 * HS), AS3(lk + 2048), 16, 0, 0); \
    __builtin_amdgcn_global_load_lds(AS1(gv + (stt)), AS3(lv), 16, 0, 0);         \
    __builtin_amdgcn_global_load_lds(AS1(gv + (stt) + (size_t)32 * TT), AS3(lv + 2048), 16, 0, 0); \
  } while (0)

  STAGE(0, 0);
  int cur = 0;

  for (int st = 0; st < TT; st += 64) {
    if (st + 64 < TT) {
      STAGE(cur ^ 1, st + 64);
      asm volatile("s_waitcnt vmcnt(4)" ::: "memory");
    } else {
      asm volatile("s_waitcnt vmcnt(0)" ::: "memory");
    }
    __builtin_amdgcn_s_barrier();
    __builtin_amdgcn_sched_barrier(0);

    const char* kbuf = (const char*)Ks[cur];
    const char* vbuf = (const char*)Vs[cur];

    // S^T = K Q^T : lane (lg,ll) holds S[q = ll][k = kb*16 + lg*4 + r]
    f4 p[4];
#pragma unroll
    for (int kb = 0; kb < 4; kb++) {
      const bfrag k0 = *(const bfrag*)(kbuf + koff0[kb]);
      const bfrag k1 = *(const bfrag*)(kbuf + koff1[kb]);
      f4 z = {0.f, 0.f, 0.f, 0.f};
      z = __builtin_amdgcn_mfma_f32_16x16x32_bf16(k0, qf[0], z, 0, 0, 0);
      p[kb] = __builtin_amdgcn_mfma_f32_16x16x32_bf16(k1, qf[1], z, 0, 0, 0);
    }

    // online softmax: tree max (depth 4), defer-max, tree sum
    {
      f4 m01, m23;
#pragma unroll
      for (int r = 0; r < 4; r++) {
        m01[r] = fmaxf(p[0][r], p[1][r]);
        m23[r] = fmaxf(p[2][r], p[3][r]);
      }
#pragma unroll
      for (int r = 0; r < 4; r++) m01[r] = fmaxf(m01[r], m23[r]);
      float pm = fmaxf(fmaxf(m01[0], m01[1]), fmaxf(m01[2], m01[3]));
      pm = fmaxf(pm, __shfl_xor(pm, 16));
      pm = fmaxf(pm, __shfl_xor(pm, 32));
      if (!__all((int)(pm <= mrun))) {   // wave-uniform branch
        const float mn = fmaxf(mrun, pm);
        const float al = exp2f(mrun - mn);
        mrun = mn;
        lrun *= al;
#pragma unroll
        for (int fo = 0; fo < 4; fo++) o[fo] *= al;
      }
#pragma unroll
      for (int kb = 0; kb < 4; kb++)
#pragma unroll
        for (int r = 0; r < 4; r++)
          p[kb][r] = exp2f(p[kb][r] - mrun);
      f4 s01, s23;
#pragma unroll
      for (int r = 0; r < 4; r++) {
        s01[r] = p[0][r] + p[1][r];
        s23[r] = p[2][r] + p[3][r];
      }
#pragma unroll
      for (int r = 0; r < 4; r++) s01[r] += s23[r];
      float rs = (s01[0] + s01[1]) + (s01[2] + s01[3]);
      rs += __shfl_xor(rs, 16);
      rs += __shfl_xor(rs, 32);
      lrun += rs;
#pragma unroll
      for (int kb = 0; kb < 4; kb++) {
        union { uint2 v; __bf16 h[4]; } w;
        w.h[0] = (__bf16)p[kb][0];
        w.h[1] = (__bf16)p[kb][1];
        w.h[2] = (__bf16)p[kb][2];
        w.h[3] = (__bf16)p[kb][3];
        *(uint2*)(pw + pwoff[kb]) = w.v;
      }
    }

    // O^T += V^T P : A = V^T rows (d), B = P rows (q).  Wave-private P.
#pragma unroll
    for (int ks = 0; ks < 2; ks++) {
      const bfrag pb = *(const bfrag*)(pw + proff[ks]);
#pragma unroll
      for (int fo = 0; fo < 4; fo++) {
        const bfrag vf = *(const bfrag*)(vbuf + voff[ks][fo]);
        o[fo] = __builtin_amdgcn_mfma_f32_16x16x32_bf16(vf, pb, o[fo], 0, 0, 0);
      }
    }

    __builtin_amdgcn_sched_barrier(0);
    __builtin_amdgcn_s_barrier();
    cur ^= 1;
  }
#undef STAGE

  // epilogue: O^T / l -> [B*T][C] bf16.  lane writes q = ll, d = fo*16+lg*4+0..3
  const int b = bh >> 4, h = bh & 15;
  const float inv = 1.0f / lrun;
  const int t = qt * 64 + wave * 16 + ll;
#pragma unroll
  for (int fo = 0; fo < 4; fo++) {
    union { uint2 v; __bf16 hh[4]; } w;
    w.hh[0] = (__bf16)(o[fo][0] * inv);
    w.hh[1] = (__bf16)(o[fo][1] * inv);
    w.hh[2] = (__bf16)(o[fo][2] * inv);
    w.hh[3] = (__bf16)(o[fo][3] * inv);
    *(uint2*)&Ao[((size_t)b * TT + t) * CC + h * HS + fo * 16 + lg * 4] = w.v;
  }
}

// ------------------------------------------------------------------
extern "C" void kernel_launch(void* const* d_in, const int* in_sizes, int n_in,
                              void* d_out, int out_size, void* d_ws, size_t ws_size,
                              hipStream_t stream) {
  const float* x    = (const float*)d_in[0];
  const float* Wq   = (const float*)d_in[1];
  const float* bq   = (const float*)d_in[2];
  const float* Wk   = (const float*)d_in[3];
  const float* bk   = (const float*)d_in[4];
  const float* Wv   = (const float*)d_in[5];
  const float* bv   = (const float*)d_in[6];
  const float* Wp   = (const float*)d_in[7];
  const float* bp   = (const float*)d_in[8];
  const float* W1   = (const float*)d_in[9];
  const float* b1   = (const float*)d_in[10];
  const float* W2   = (const float*)d_in[11];
  const float* b2   = (const float*)d_in[12];
  const float* ln1w = (const float*)d_in[13];
  const float* ln1b = (const float*)d_in[14];
  const float* ln2w = (const float*)d_in[15];
  const float* ln2b = (const float*)d_in[16];
  float* dout = (float*)d_out;

  char* ws = (char*)d_ws;
  u16* wqkv = (u16*)(ws + 0);          // [3072][1024]  (dead after qkv)
  u16* wpt  = (u16*)(ws + 6291456);    // [1024][1024]  (dead after proj)
  u16* w1t  = (u16*)(ws + 8388608);    // [4096][1024]  (dead after ffn1)
  u16* w2t  = (u16*)(ws + 16777216);   // [1024][4096]
  u16* xn   = (u16*)(ws + 25165824);   // [4096][1024]  (reused for LN2)
  u16* qb   = (u16*)(ws + 33554432);   // [32][2048][64]
  u16* kb   = (u16*)(ws + 41943040);
  u16* vb   = (u16*)(ws + 50331648);
  u16* vt   = (u16*)(ws + 58720256);   // [32][64][2048]
  u16* ao   = (u16*)(ws + 67108864);   // [4096][1024]
  u16* hb   = qb;                      // FFN hidden overlays q/k/v/vt
  u16* pk0  = (u16*)(ws + 0);          // ffn2 partial over wqkv+wpt
  u16* pk1  = (u16*)(ws + 8388608);    // ffn2 partial over w1t

  dim3 blk256(256);
  dim3 blkT(32, 8);

  // weight prep: transpose to [N][K] bf16
  tr_f32_bf16<<<dim3(2, 32, 16), blkT, 0, stream>>>(Wq, wqkv,               1024,   64, 65536LL, 65536LL, 1024);
  tr_f32_bf16<<<dim3(2, 32, 16), blkT, 0, stream>>>(Wk, wqkv + 1024 * 1024, 1024,   64, 65536LL, 65536LL, 1024);
  tr_f32_bf16<<<dim3(2, 32, 16), blkT, 0, stream>>>(Wv, wqkv + 2048 * 1024, 1024,   64, 65536LL, 65536LL, 1024);
  tr_f32_bf16<<<dim3(32, 32, 1),  blkT, 0, stream>>>(Wp, wpt, 1024, 1024, 0LL, 0LL, 1024);
  tr_f32_bf16<<<dim3(128, 32, 1), blkT, 0, stream>>>(W1, w1t, 1024, 4096, 0LL, 0LL, 1024);
  tr_f32_bf16<<<dim3(32, 128, 1), blkT, 0, stream>>>(W2, w2t, 4096, 1024, 0LL, 0LL, 4096);

  // LN1 -> xn (bf16)
  ln_kernel<<<dim3(MT), blk256, 0, stream>>>(x, ln1w, ln1b, xn);

  // QKV projection (q pre-scaled by C^-0.5 * log2e)
  gemm_qkv<<<dim3(24, 32), blk256, 0, stream>>>(xn, wqkv, bq, bk, bv, qb, kb, vb);

  // V -> Vt [bh][64][2048]
  tr_bf16<<<dim3(2, 64, 32), blkT, 0, stream>>>(vb, vt, 2048, 64, 131072LL, 131072LL, 2048);

  // attention (QBLK=64, XCD-affinity remap inside kernel)
  attn_kernel<<<dim3(32, 32), blk256, 0, stream>>>(qb, kb, vt, ao);

  // out = x + ao @ Wp + bp   (f32, into d_out)
  gemm_proj<<<dim3(16, 32), blk256, 0, stream>>>(ao, wpt, bp, x, dout);

  // LN2 -> xn (reuse)
  ln_kernel<<<dim3(MT), blk256, 0, stream>>>(dout, ln2w, ln2b, xn);

  // FFN
  gemm_ffn1<<<dim3(32, 32), blk256, 0, stream>>>(xn, w1t, b1, hb);
  gemm_ffn2sk<<<dim3(8, 32, 2), blk256, 0, stream>>>(hb, w2t, pk0, pk1);
  ffn2_reduce<<<dim3(MT * CC / 8 / 256), blk256, 0, stream>>>(pk0, pk1, b2, dout);
}

// Round 10
// 271.890 us; speedup vs baseline: 1.1044x; 1.0196x over previous
//
#include <hip/hip_runtime.h>
#include <math.h>

// ---- problem dims (B=2, T=2048, C=1024, H=16, HS=64) ----
#define BB 2
#define TT 2048
#define CC 1024
#define HH 16
#define HS 64
#define MT 4096   // B*T
#define FF 4096   // 4*C

typedef unsigned short u16;
typedef __bf16 bfrag __attribute__((ext_vector_type(8)));
typedef float f4 __attribute__((ext_vector_type(4)));
typedef float f16v __attribute__((ext_vector_type(16)));

#define AS1(p) ((const __attribute__((address_space(1))) void*)(p))
#define AS3(p) ((__attribute__((address_space(3))) void*)(p))

__device__ __forceinline__ u16 f2bf(float f) {
  union { float f; unsigned u; } a; a.f = f;
  return (u16)((a.u + 0x7fffu + ((a.u >> 16) & 1u)) >> 16);
}
__device__ __forceinline__ float bf2f(u16 u) {
  union { unsigned u; float f; } a; a.u = ((unsigned)u) << 16; return a.f;
}

// XOR-swizzle for 128-byte-row LDS tiles (attention)
__device__ __forceinline__ int swz128(int byteoff) {
  return byteoff ^ (((byteoff >> 7) & 7) << 4);
}
// XOR-swizzle for 64-byte-row LDS tiles (GEMM A/B)
__device__ __forceinline__ int swzAB(int byteoff) {
  return byteoff ^ (((byteoff >> 7) & 3) << 4);
}

// XCD-aware chunked swizzle (T1).  Requires nwg % 8 == 0.
#define XCD_SWZ_2D(BX, BY)                                                     \
  int _fl = (int)blockIdx.y * gridDim.x + blockIdx.x;                          \
  const int _nw = gridDim.x * gridDim.y;                                       \
  _fl = (_fl & 7) * (_nw >> 3) + (_fl >> 3);                                   \
  const int BX = _fl % gridDim.x;                                              \
  const int BY = _fl / gridDim.x;

// ------------------------------------------------------------------
// Tiled transpose f32 -> bf16.
// ------------------------------------------------------------------
__global__ void tr_f32_bf16(const float* __restrict__ src, u16* __restrict__ dst,
                            int R, int Cc, long long sb, long long db, int dld) {
  __shared__ float t[32][33];
  const int bz = blockIdx.z;
  const int r0 = blockIdx.y * 32, c0 = blockIdx.x * 32;
  const int tx = threadIdx.x, ty = threadIdx.y;
  const float* s = src + bz * sb;
  u16* d = dst + bz * db;
#pragma unroll
  for (int i = 0; i < 4; i++)
    t[ty + i * 8][tx] = s[(size_t)(r0 + ty + i * 8) * Cc + c0 + tx];
  __syncthreads();
#pragma unroll
  for (int i = 0; i < 4; i++)
    d[(size_t)(c0 + ty + i * 8) * dld + r0 + tx] = f2bf(t[tx][ty + i * 8]);
}

// bf16 -> bf16 transpose (for V)
__global__ void tr_bf16(const u16* __restrict__ src, u16* __restrict__ dst,
                        int R, int Cc, long long sb, long long db, int dld) {
  __shared__ u16 t[32][33];
  const int bz = blockIdx.z;
  const int r0 = blockIdx.y * 32, c0 = blockIdx.x * 32;
  const int tx = threadIdx.x, ty = threadIdx.y;
  const u16* s = src + bz * sb;
  u16* d = dst + bz * db;
#pragma unroll
  for (int i = 0; i < 4; i++)
    t[ty + i * 8][tx] = s[(size_t)(r0 + ty + i * 8) * Cc + c0 + tx];
  __syncthreads();
#pragma unroll
  for (int i = 0; i < 4; i++)
    d[(size_t)(c0 + ty + i * 8) * dld + r0 + tx] = t[tx][ty + i * 8];
}

// ------------------------------------------------------------------
// LayerNorm: one block (256 thr) per row of [4096][1024] f32 -> bf16
// ------------------------------------------------------------------
__global__ __launch_bounds__(256) void ln_kernel(
    const float* __restrict__ x, const float* __restrict__ w,
    const float* __restrict__ b, u16* __restrict__ y) {
  const int row = blockIdx.x, tid = threadIdx.x;
  const float4 v = reinterpret_cast<const float4*>(x + (size_t)row * CC)[tid];
  float s = v.x + v.y + v.z + v.w;
  float s2 = v.x * v.x + v.y * v.y + v.z * v.z + v.w * v.w;
#pragma unroll
  for (int off = 32; off >= 1; off >>= 1) {
    s += __shfl_xor(s, off);
    s2 += __shfl_xor(s2, off);
  }
  __shared__ float ps[4], ps2[4];
  const int wave = tid >> 6, lane = tid & 63;
  if (lane == 0) { ps[wave] = s; ps2[wave] = s2; }
  __syncthreads();
  s = ps[0] + ps[1] + ps[2] + ps[3];
  s2 = ps2[0] + ps2[1] + ps2[2] + ps2[3];
  const float mu = s * (1.f / CC);
  const float rstd = rsqrtf(s2 * (1.f / CC) - mu * mu + 1e-5f);
  const float4 wv = reinterpret_cast<const float4*>(w)[tid];
  const float4 bv = reinterpret_cast<const float4*>(b)[tid];
  ushort4 o;
  o.x = f2bf((v.x - mu) * rstd * wv.x + bv.x);
  o.y = f2bf((v.y - mu) * rstd * wv.y + bv.y);
  o.z = f2bf((v.z - mu) * rstd * wv.z + bv.z);
  o.w = f2bf((v.w - mu) * rstd * wv.w + bv.w);
  reinterpret_cast<ushort4*>(y + (size_t)row * CC)[tid] = o;
}

// ------------------------------------------------------------------
// GEMM core (depth-3 pipeline): 128 x (NJ*32) tile.  Unchanged.
// ------------------------------------------------------------------
template<int NJ>
__device__ __forceinline__ void gemm_core(
    u16* smem, const u16* __restrict__ A, const u16* __restrict__ Bt,
    int K, int lda, int ldb, int bmi, int bni, f4 (&acc)[4][NJ]) {
  constexpr int BN = NJ * 32;
  constexpr int BBUF = BN * 32;
  u16* As = smem;
  u16* Bs = smem + 3 * 4096;
  const int tid = threadIdx.x;
  const int wave = tid >> 6, lane = tid & 63;
  const int wm = wave >> 1, wn = wave & 1;
  const int lg = lane >> 4, ll = lane & 15;

  const int trow = tid >> 2;
  const int tch  = (tid & 3) ^ ((trow >> 1) & 3);
  const u16* ga = A + (size_t)(bmi * 128 + trow) * lda + tch * 8;
  const u16* gb = Bt + (size_t)(bni * BN + trow) * ldb + tch * 8;
  const size_t g64a = (size_t)64 * lda;
  const size_t g64b = (size_t)64 * ldb;
  const int nt = K >> 5;

  auto GSTAGE = [&](int bi, int kt) {
    u16* la = &As[bi * 4096 + tid * 8];
    u16* lb = &Bs[bi * BBUF + tid * 8];
    const u16* gA = ga + kt * 32;
    const u16* gB = gb + kt * 32;
    __builtin_amdgcn_global_load_lds(AS1(gA), AS3(la), 16, 0, 0);
    __builtin_amdgcn_global_load_lds(AS1(gA + g64a), AS3(la + 2048), 16, 0, 0);
    __builtin_amdgcn_global_load_lds(AS1(gB), AS3(lb), 16, 0, 0);
    if constexpr (NJ == 4)
      __builtin_amdgcn_global_load_lds(AS1(gB + g64b), AS3(lb + 2048), 16, 0, 0);
  };

  GSTAGE(0, 0);
  GSTAGE(1, 1);
  GSTAGE(2, 2);
  int bi = 0;
  for (int t = 0; t < nt; t++) {
    const int ahead = nt - 1 - t;
    if constexpr (NJ == 4) {
      if (ahead >= 2)      asm volatile("s_waitcnt vmcnt(8)" ::: "memory");
      else if (ahead == 1) asm volatile("s_waitcnt vmcnt(4)" ::: "memory");
      else                 asm volatile("s_waitcnt vmcnt(0)" ::: "memory");
    } else {
      if (ahead >= 2)      asm volatile("s_waitcnt vmcnt(6)" ::: "memory");
      else if (ahead == 1) asm volatile("s_waitcnt vmcnt(3)" ::: "memory");
      else                 asm volatile("s_waitcnt vmcnt(0)" ::: "memory");
    }
    __builtin_amdgcn_s_barrier();
    __builtin_amdgcn_sched_barrier(0);

    const char* as_ = (const char*)(As + bi * 4096);
    const char* bs_ = (const char*)(Bs + bi * BBUF);
    bfrag af[4], bf[NJ];
#pragma unroll
    for (int i = 0; i < 4; i++)
      af[i] = *(const bfrag*)(as_ + swzAB((wm * 64 + i * 16 + ll) * 64 + lg * 16));
#pragma unroll
    for (int j = 0; j < NJ; j++)
      bf[j] = *(const bfrag*)(bs_ + swzAB((wn * (BN / 2) + j * 16 + ll) * 64 + lg * 16));

    __builtin_amdgcn_s_setprio(1);
#pragma unroll
    for (int i = 0; i < 4; i++)
#pragma unroll
      for (int j = 0; j < NJ; j++)
        acc[i][j] = __builtin_amdgcn_mfma_f32_16x16x32_bf16(af[i], bf[j], acc[i][j], 0, 0, 0);
    __builtin_amdgcn_s_setprio(0);

    __builtin_amdgcn_sched_barrier(0);
    __builtin_amdgcn_s_barrier();
    if (t + 3 < nt) GSTAGE(bi, t + 3);
    bi = (bi == 2) ? 0 : bi + 1;
  }
}

#define EPI_COORDS                                              \
  const int tid = threadIdx.x;                                  \
  const int wave = tid >> 6, lane = tid & 63;                   \
  const int wm = wave >> 1, wn = wave & 1;                      \
  const int lg = lane >> 4, ll = lane & 15;

// QKV: N=3072 (q|k|v), bias add, fold C^-0.5*log2e into q, LDS-staged scatter.
__global__ __launch_bounds__(256, 3) void gemm_qkv(
    const u16* __restrict__ A, const u16* __restrict__ Bt,
    const float* __restrict__ bq, const float* __restrict__ bk,
    const float* __restrict__ bv,
    u16* __restrict__ q, u16* __restrict__ k, u16* __restrict__ v) {
  __shared__ u16 smem[24576];
  XCD_SWZ_2D(bx, by)
  f4 acc[4][4] = {};
  gemm_core<4>(smem, A, Bt, CC, CC, CC, by, bx, acc);
  EPI_COORDS
  __syncthreads();
#pragma unroll
  for (int j = 0; j < 4; j++) {
    const int n = bx * 128 + wn * 64 + j * 16 + ll;
    const int sec = n >> 10, nn = n & 1023;
    const float bias = (sec == 0 ? bq : (sec == 1 ? bk : bv))[nn];
    const float scale = (sec == 0) ? 0.045084220027780106f : 1.0f;
#pragma unroll
    for (int i = 0; i < 4; i++)
#pragma unroll
      for (int r = 0; r < 4; r++)
        smem[(wm * 64 + i * 16 + lg * 4 + r) * 136 + wn * 64 + j * 16 + ll] =
            f2bf((acc[i][j][r] + bias) * scale);
  }
  __syncthreads();
  const int rr = tid >> 4, cb = (tid & 15) * 8;
#pragma unroll
  for (int R = 0; R < 8; R++) {
    const int row = R * 16 + rr;
    const int m = by * 128 + row, b = m >> 11, t = m & 2047;
    const int n = bx * 128 + cb;
    const int sec = n >> 10, nn = n & 1023, h = nn >> 6, d = nn & 63;
    u16* dst = sec == 0 ? q : (sec == 1 ? k : v);
    *(uint4*)&dst[(((size_t)b * HH + h) * TT + t) * HS + d] =
        *(const uint4*)&smem[row * 136 + cb];
  }
}

// FFN1: h = gelu_exact(A @ W1 + b1) -> bf16, LDS-staged writeback.
__global__ __launch_bounds__(256, 3) void gemm_ffn1(
    const u16* __restrict__ A, const u16* __restrict__ Bt,
    const float* __restrict__ b1, u16* __restrict__ hb) {
  __shared__ u16 smem[24576];
  XCD_SWZ_2D(bx, by)
  f4 acc[4][4] = {};
  gemm_core<4>(smem, A, Bt, CC, CC, CC, by, bx, acc);
  EPI_COORDS
  __syncthreads();
#pragma unroll
  for (int j = 0; j < 4; j++) {
    const int n = bx * 128 + wn * 64 + j * 16 + ll;
    const float bias = b1[n];
#pragma unroll
    for (int i = 0; i < 4; i++)
#pragma unroll
      for (int r = 0; r < 4; r++) {
        const float t = acc[i][j][r] + bias;
        const float g = 0.5f * t * (1.0f + erff(t * 0.70710678118654752f));
        smem[(wm * 64 + i * 16 + lg * 4 + r) * 136 + wn * 64 + j * 16 + ll] = f2bf(g);
      }
  }
  __syncthreads();
  const int rr = tid >> 4, cb = (tid & 15) * 8;
#pragma unroll
  for (int R = 0; R < 8; R++) {
    const int row = R * 16 + rr;
    *(uint4*)&hb[(size_t)(by * 128 + row) * FF + bx * 128 + cb] =
        *(const uint4*)&smem[row * 136 + cb];
  }
}

// FFN2 split-K chunk GEMM -> bf16 partials.
__global__ __launch_bounds__(256, 3) void gemm_ffn2sk(
    const u16* __restrict__ A, const u16* __restrict__ Bt,
    u16* __restrict__ p0, u16* __restrict__ p1) {
  __shared__ u16 smem[24576];
  int _fl = ((int)blockIdx.z * gridDim.y + blockIdx.y) * gridDim.x + blockIdx.x;
  const int _nw = gridDim.x * gridDim.y * gridDim.z;
  _fl = (_fl & 7) * (_nw >> 3) + (_fl >> 3);
  const int bx = _fl % gridDim.x;
  const int by = (_fl / gridDim.x) % gridDim.y;
  const int bz = _fl / (gridDim.x * gridDim.y);

  f4 acc[4][4] = {};
  gemm_core<4>(smem, A + bz * 2048, Bt + bz * 2048, 2048, FF, FF, by, bx, acc);
  EPI_COORDS
  __syncthreads();
#pragma unroll
  for (int j = 0; j < 4; j++)
#pragma unroll
    for (int i = 0; i < 4; i++)
#pragma unroll
      for (int r = 0; r < 4; r++)
        smem[(wm * 64 + i * 16 + lg * 4 + r) * 136 + wn * 64 + j * 16 + ll] =
            f2bf(acc[i][j][r]);
  __syncthreads();
  u16* pp = bz ? p1 : p0;
  const int rr = tid >> 4, cb = (tid & 15) * 8;
#pragma unroll
  for (int R = 0; R < 8; R++) {
    const int row = R * 16 + rr;
    *(uint4*)&pp[(size_t)(by * 128 + row) * CC + bx * 128 + cb] =
        *(const uint4*)&smem[row * 136 + cb];
  }
}

// FFN2 reduce: dout = dout(residual) + b2 + p0 + p1.
__global__ __launch_bounds__(256) void ffn2_reduce(
    const u16* __restrict__ p0, const u16* __restrict__ p1,
    const float* __restrict__ b2, float* __restrict__ dout) {
  const int gid = blockIdx.x * 256 + threadIdx.x;
  const int n0 = (gid * 8) & (CC - 1);
  const uint4 a = ((const uint4*)p0)[gid];
  const uint4 c = ((const uint4*)p1)[gid];
  const u16* au = (const u16*)&a;
  const u16* cu = (const u16*)&c;
  float4 d0 = ((const float4*)dout)[gid * 2];
  float4 d1 = ((const float4*)dout)[gid * 2 + 1];
  const float4 w0 = *(const float4*)&b2[n0];
  const float4 w1 = *(const float4*)&b2[n0 + 4];
  d0.x += w0.x + bf2f(au[0]) + bf2f(cu[0]);
  d0.y += w0.y + bf2f(au[1]) + bf2f(cu[1]);
  d0.z += w0.z + bf2f(au[2]) + bf2f(cu[2]);
  d0.w += w0.w + bf2f(au[3]) + bf2f(cu[3]);
  d1.x += w1.x + bf2f(au[4]) + bf2f(cu[4]);
  d1.y += w1.y + bf2f(au[5]) + bf2f(cu[5]);
  d1.z += w1.z + bf2f(au[6]) + bf2f(cu[6]);
  d1.w += w1.w + bf2f(au[7]) + bf2f(cu[7]);
  ((float4*)dout)[gid * 2] = d0;
  ((float4*)dout)[gid * 2 + 1] = d1;
}

// PROJ: out = x + (A @ Wp + bp) -> f32 (= d_out).  BN=64, NJ=2.
__global__ __launch_bounds__(256, 3) void gemm_proj(
    const u16* __restrict__ A, const u16* __restrict__ Bt,
    const float* __restrict__ bp, const float* __restrict__ x,
    float* __restrict__ outw) {
  __shared__ u16 smem[18432];
  XCD_SWZ_2D(bx, by)
  f4 acc[4][2] = {};
  gemm_core<2>(smem, A, Bt, CC, CC, CC, by, bx, acc);
  EPI_COORDS
#pragma unroll
  for (int i = 0; i < 4; i++)
#pragma unroll
    for (int j = 0; j < 2; j++) {
      const int n = bx * 64 + wn * 32 + j * 16 + ll;
      const float bias = bp[n];
#pragma unroll
      for (int r = 0; r < 4; r++) {
        const int m = by * 128 + wm * 64 + i * 16 + lg * 4 + r;
        const size_t idx = (size_t)m * CC + n;
        outw[idx] = acc[i][j][r] + bias + x[idx];
      }
    }
}

// ------------------------------------------------------------------
// Flash attention fwd v6: 32x32 MFMA swapped-operand, IN-REGISTER P
// (cvt_pk_bf16 + permlane32_swap, T12) -- no P LDS traffic, no shuffle
// reductions on the DS pipe.  Each wave owns 32 q-rows (QBLK=128/block,
// grid 512 = 2 blocks/CU).  K/V staging identical to v5 (64x64 swizzled
// double-buffer, counted vmcnt).  XCD-affinity remap, defer-max, exp2.
//
// QK^T: S^T[kv][q] = mfma_32x32x16(A=K, B=Q): lane l holds, reg r:
//   P[q=l&31][kv = (r&3) + 8*(r>>2) + 4*(l>>5)]  (C-layout verified m74/m101)
// PV B-frag needs lane l: P[kv=ks*16+(l>>5)*8+j][q=l&31].  Mapping:
//   a0=cvtpk(p0,p1) a1=cvtpk(p2,p3) a2=cvtpk(p4,p5) a3=cvtpk(p6,p7)
//   swap(a2,a0) -> V2=a2', V0=a0'; swap(a3,a1) -> V3=a3', V1=a1'
// ------------------------------------------------------------------
__global__ __launch_bounds__(256, 2) void attn_kernel(
    const u16* __restrict__ Q, const u16* __restrict__ Kb,
    const u16* __restrict__ Vt, u16* __restrict__ Ao) {
  __shared__ __align__(1024) u16 Ks[2][64 * 64];  // [s:64][d:64], swizzled
  __shared__ __align__(1024) u16 Vs[2][64 * 64];  // [d:64][s:64], swizzled

  // XCD-affinity remap: 512 blocks; xcd = fl&7 owns 4 bh x 16 qt.
  const int fl = (int)blockIdx.y * gridDim.x + blockIdx.x;
  const int idx = fl >> 3;
  const int bh = (idx >> 4) * 8 + (fl & 7);
  const int qt = idx & 15;

  const int tid = threadIdx.x, wave = tid >> 6, lane = tid & 63;
  const int l31 = lane & 31, hi = lane >> 5;

  // Q as MFMA B-operand: lane holds Q[q=l31][d = t*16 + hi*8 + 0..7]
  bfrag qf[4];
  const u16* Qb = Q + ((size_t)bh * TT + qt * 128 + wave * 32) * HS;
#pragma unroll
  for (int t = 0; t < 4; t++)
    qf[t] = *(const bfrag*)&Qb[l31 * HS + t * 16 + hi * 8];

  f16v o0 = {}, o1 = {};           // O^T accum: dhalf 0/1, q = l31
  float mrun = -INFINITY, lrun = 0.f;

  const int trow = tid >> 3;
  const int tch  = (tid & 7) ^ (trow & 7);
  const u16* gk = Kb + ((size_t)bh * TT + trow) * HS + tch * 8;
  const u16* gv = Vt + ((size_t)bh * HS + trow) * TT + tch * 8;

  // hoisted swizzled byte offsets
  int koff[2][4], voff[2][2][2];   // [sub][t] / [dhalf][sub][ks]
#pragma unroll
  for (int sub = 0; sub < 2; sub++) {
#pragma unroll
    for (int t = 0; t < 4; t++)
      koff[sub][t] = swz128((sub * 32 + l31) * 128 + t * 32 + hi * 16);
#pragma unroll
    for (int dh = 0; dh < 2; dh++)
#pragma unroll
      for (int ks = 0; ks < 2; ks++)
        voff[dh][sub][ks] = swz128((dh * 32 + l31) * 128 + sub * 64 + ks * 32 + hi * 16);
  }

#define STAGE(bufi, stt)                                                          \
  do {                                                                            \
    u16* lk = &Ks[bufi][tid * 8];                                                 \
    u16* lv = &Vs[bufi][tid * 8];                                                 \
    __builtin_amdgcn_global_load_lds(AS1(gk + (size_t)(stt) * HS), AS3(lk), 16, 0, 0); \
    __builtin_amdgcn_global_load_lds(AS1(gk + (size_t)(stt) * HS + 32 * HS), AS3(lk + 2048), 16, 0, 0); \
    __builtin_amdgcn_global_load_lds(AS1(gv + (stt)), AS3(lv), 16, 0, 0);         \
    __builtin_amdgcn_global_load_lds(AS1(gv + (stt) + (size_t)32 * TT), AS3(lv + 2048), 16, 0, 0); \
  } while (0)

  STAGE(0, 0);
  int cur = 0;

  for (int st = 0; st < TT; st += 64) {
    if (st + 64 < TT) {
      STAGE(cur ^ 1, st + 64);
      asm volatile("s_waitcnt vmcnt(4)" ::: "memory");
    } else {
      asm volatile("s_waitcnt vmcnt(0)" ::: "memory");
    }
    __builtin_amdgcn_s_barrier();
    __builtin_amdgcn_sched_barrier(0);

    const char* kbuf = (const char*)Ks[cur];
    const char* vbuf = (const char*)Vs[cur];

    // S^T = K Q^T per 32-kv subtile
    f16v s0 = {}, s1 = {};
#pragma unroll
    for (int t = 0; t < 4; t++) {
      const bfrag kf0 = *(const bfrag*)(kbuf + koff[0][t]);
      s0 = __builtin_amdgcn_mfma_f32_32x32x16_bf16(kf0, qf[t], s0, 0, 0, 0);
    }
#pragma unroll
    for (int t = 0; t < 4; t++) {
      const bfrag kf1 = *(const bfrag*)(kbuf + koff[1][t]);
      s1 = __builtin_amdgcn_mfma_f32_32x32x16_bf16(kf1, qf[t], s1, 0, 0, 0);
    }

    // row max over 64 kv: in-lane tree + one cross-half exchange
    float t8[8];
#pragma unroll
    for (int j = 0; j < 8; j++) t8[j] = fmaxf(s0[j], s0[j + 8]);
#pragma unroll
    for (int j = 0; j < 8; j++) t8[j] = fmaxf(t8[j], fmaxf(s1[j], s1[j + 8]));
#pragma unroll
    for (int j = 0; j < 4; j++) t8[j] = fmaxf(t8[j], t8[j + 4]);
    float pm = fmaxf(fmaxf(t8[0], t8[1]), fmaxf(t8[2], t8[3]));
    pm = fmaxf(pm, __shfl_xor(pm, 32));

    if (!__all((int)(pm <= mrun))) {   // defer-max (wave-uniform)
      const float mn = fmaxf(mrun, pm);
      const float al = exp2f(mrun - mn);
      mrun = mn;
      lrun *= al;
#pragma unroll
      for (int j = 0; j < 16; j++) { o0[j] *= al; o1[j] *= al; }
    }

    // exp2 + sum + pack (per sub), P stays in registers
    unsigned pf[2][2][4];  // [sub][ks][vgpr]
    float rs = 0.f;
#pragma unroll
    for (int j = 0; j < 16; j++) { s0[j] = exp2f(s0[j] - mrun); rs += s0[j]; }
#pragma unroll
    for (int j = 0; j < 16; j++) { s1[j] = exp2f(s1[j] - mrun); rs += s1[j]; }
    rs += __shfl_xor(rs, 32);
    lrun += rs;

#pragma unroll
    for (int sub = 0; sub < 2; sub++) {
      const f16v& sv = sub ? s1 : s0;
      unsigned a0, a1, a2, a3, a4, a5, a6, a7;
      asm("v_cvt_pk_bf16_f32 %0, %1, %2" : "=v"(a0) : "v"(sv[0]),  "v"(sv[1]));
      asm("v_cvt_pk_bf16_f32 %0, %1, %2" : "=v"(a1) : "v"(sv[2]),  "v"(sv[3]));
      asm("v_cvt_pk_bf16_f32 %0, %1, %2" : "=v"(a2) : "v"(sv[4]),  "v"(sv[5]));
      asm("v_cvt_pk_bf16_f32 %0, %1, %2" : "=v"(a3) : "v"(sv[6]),  "v"(sv[7]));
      asm("v_cvt_pk_bf16_f32 %0, %1, %2" : "=v"(a4) : "v"(sv[8]),  "v"(sv[9]));
      asm("v_cvt_pk_bf16_f32 %0, %1, %2" : "=v"(a5) : "v"(sv[10]), "v"(sv[11]));
      asm("v_cvt_pk_bf16_f32 %0, %1, %2" : "=v"(a6) : "v"(sv[12]), "v"(sv[13]));
      asm("v_cvt_pk_bf16_f32 %0, %1, %2" : "=v"(a7) : "v"(sv[14]), "v"(sv[15]));
      asm("v_permlane32_swap_b32 %0, %1" : "+v"(a2), "+v"(a0));
      asm("v_permlane32_swap_b32 %0, %1" : "+v"(a3), "+v"(a1));
      asm("v_permlane32_swap_b32 %0, %1" : "+v"(a6), "+v"(a4));
      asm("v_permlane32_swap_b32 %0, %1" : "+v"(a7), "+v"(a5));
      pf[sub][0][0] = a0; pf[sub][0][1] = a1; pf[sub][0][2] = a2; pf[sub][0][3] = a3;
      pf[sub][1][0] = a4; pf[sub][1][1] = a5; pf[sub][1][2] = a6; pf[sub][1][3] = a7;
    }

    // O^T += V^T P
#pragma unroll
    for (int sub = 0; sub < 2; sub++)
#pragma unroll
      for (int ks = 0; ks < 2; ks++) {
        union { unsigned u[4]; bfrag b; } pb;
        pb.u[0] = pf[sub][ks][0]; pb.u[1] = pf[sub][ks][1];
        pb.u[2] = pf[sub][ks][2]; pb.u[3] = pf[sub][ks][3];
        const bfrag vf0 = *(const bfrag*)(vbuf + voff[0][sub][ks]);
        o0 = __builtin_amdgcn_mfma_f32_32x32x16_bf16(vf0, pb.b, o0, 0, 0, 0);
        const bfrag vf1 = *(const bfrag*)(vbuf + voff[1][sub][ks]);
        o1 = __builtin_amdgcn_mfma_f32_32x32x16_bf16(vf1, pb.b, o1, 0, 0, 0);
      }

    __builtin_amdgcn_sched_barrier(0);
    __builtin_amdgcn_s_barrier();
    cur ^= 1;
  }
#undef STAGE

  // epilogue: O^T/l -> [B*T][C] bf16.
  // lane: q = l31, d = dh*32 + 8*rq + 4*hi + ri  (rq=reg>>2, ri=reg&3)
  const int b = bh >> 4, h = bh & 15;
  const float inv = 1.0f / lrun;
  const int t = qt * 128 + wave * 32 + l31;
  u16* aorow = Ao + ((size_t)b * TT + t) * CC + h * HS;
#pragma unroll
  for (int dh = 0; dh < 2; dh++) {
    const f16v& ov = dh ? o1 : o0;
#pragma unroll
    for (int rq = 0; rq < 4; rq++) {
      union { uint2 v; __bf16 hh[4]; } w;
      w.hh[0] = (__bf16)(ov[rq * 4 + 0] * inv);
      w.hh[1] = (__bf16)(ov[rq * 4 + 1] * inv);
      w.hh[2] = (__bf16)(ov[rq * 4 + 2] * inv);
      w.hh[3] = (__bf16)(ov[rq * 4 + 3] * inv);
      *(uint2*)&aorow[dh * 32 + rq * 8 + hi * 4] = w.v;
    }
  }
}

// ------------------------------------------------------------------
extern "C" void kernel_launch(void* const* d_in, const int* in_sizes, int n_in,
                              void* d_out, int out_size, void* d_ws, size_t ws_size,
                              hipStream_t stream) {
  const float* x    = (const float*)d_in[0];
  const float* Wq   = (const float*)d_in[1];
  const float* bq   = (const float*)d_in[2];
  const float* Wk   = (const float*)d_in[3];
  const float* bk   = (const float*)d_in[4];
  const float* Wv   = (const float*)d_in[5];
  const float* bv   = (const float*)d_in[6];
  const float* Wp   = (const float*)d_in[7];
  const float* bp   = (const float*)d_in[8];
  const float* W1   = (const float*)d_in[9];
  const float* b1   = (const float*)d_in[10];
  const float* W2   = (const float*)d_in[11];
  const float* b2   = (const float*)d_in[12];
  const float* ln1w = (const float*)d_in[13];
  const float* ln1b = (const float*)d_in[14];
  const float* ln2w = (const float*)d_in[15];
  const float* ln2b = (const float*)d_in[16];
  float* dout = (float*)d_out;

  char* ws = (char*)d_ws;
  u16* wqkv = (u16*)(ws + 0);          // [3072][1024]  (dead after qkv)
  u16* wpt  = (u16*)(ws + 6291456);    // [1024][1024]  (dead after proj)
  u16* w1t  = (u16*)(ws + 8388608);    // [4096][1024]  (dead after ffn1)
  u16* w2t  = (u16*)(ws + 16777216);   // [1024][4096]
  u16* xn   = (u16*)(ws + 25165824);   // [4096][1024]  (reused for LN2)
  u16* qb   = (u16*)(ws + 33554432);   // [32][2048][64]
  u16* kb   = (u16*)(ws + 41943040);
  u16* vb   = (u16*)(ws + 50331648);
  u16* vt   = (u16*)(ws + 58720256);   // [32][64][2048]
  u16* ao   = (u16*)(ws + 67108864);   // [4096][1024]
  u16* hb   = qb;                      // FFN hidden overlays q/k/v/vt
  u16* pk0  = (u16*)(ws + 0);          // ffn2 partial over wqkv+wpt
  u16* pk1  = (u16*)(ws + 8388608);    // ffn2 partial over w1t

  dim3 blk256(256);
  dim3 blkT(32, 8);

  // weight prep: transpose to [N][K] bf16
  tr_f32_bf16<<<dim3(2, 32, 16), blkT, 0, stream>>>(Wq, wqkv,               1024,   64, 65536LL, 65536LL, 1024);
  tr_f32_bf16<<<dim3(2, 32, 16), blkT, 0, stream>>>(Wk, wqkv + 1024 * 1024, 1024,   64, 65536LL, 65536LL, 1024);
  tr_f32_bf16<<<dim3(2, 32, 16), blkT, 0, stream>>>(Wv, wqkv + 2048 * 1024, 1024,   64, 65536LL, 65536LL, 1024);
  tr_f32_bf16<<<dim3(32, 32, 1),  blkT, 0, stream>>>(Wp, wpt, 1024, 1024, 0LL, 0LL, 1024);
  tr_f32_bf16<<<dim3(128, 32, 1), blkT, 0, stream>>>(W1, w1t, 1024, 4096, 0LL, 0LL, 1024);
  tr_f32_bf16<<<dim3(32, 128, 1), blkT, 0, stream>>>(W2, w2t, 4096, 1024, 0LL, 0LL, 4096);

  // LN1 -> xn (bf16)
  ln_kernel<<<dim3(MT), blk256, 0, stream>>>(x, ln1w, ln1b, xn);

  // QKV projection (q pre-scaled by C^-0.5 * log2e)
  gemm_qkv<<<dim3(24, 32), blk256, 0, stream>>>(xn, wqkv, bq, bk, bv, qb, kb, vb);

  // V -> Vt [bh][64][2048]
  tr_bf16<<<dim3(2, 64, 32), blkT, 0, stream>>>(vb, vt, 2048, 64, 131072LL, 131072LL, 2048);

  // attention (QBLK=128/block, 512 blocks, XCD-affinity remap inside)
  attn_kernel<<<dim3(16, 32), blk256, 0, stream>>>(qb, kb, vt, ao);

  // out = x + ao @ Wp + bp   (f32, into d_out)
  gemm_proj<<<dim3(16, 32), blk256, 0, stream>>>(ao, wpt, bp, x, dout);

  // LN2 -> xn (reuse)
  ln_kernel<<<dim3(MT), blk256, 0, stream>>>(dout, ln2w, ln2b, xn);

  // FFN
  gemm_ffn1<<<dim3(32, 32), blk256, 0, stream>>>(xn, w1t, b1, hb);
  gemm_ffn2sk<<<dim3(8, 32, 2), blk256, 0, stream>>>(hb, w2t, pk0, pk1);
  ffn2_reduce<<<dim3(MT * CC / 8 / 256), blk256, 0, stream>>>(pk0, pk1, b2, dout);
}